// Round 1
// baseline (1177.687 us; speedup 1.0000x reference)
//
#include <hip/hip_runtime.h>
#include <stdint.h>

// Problem constants: B=4, T=2048, D=1024, H=16, HS=64
typedef __attribute__((ext_vector_type(8))) short short8;
typedef __attribute__((ext_vector_type(4))) float f32x4;

__device__ __forceinline__ unsigned short f2bf(float f) {
  unsigned u = __float_as_uint(f);
  u = u + 0x7FFFu + ((u >> 16) & 1u);  // RNE
  return (unsigned short)(u >> 16);
}
__device__ __forceinline__ void unpack2(unsigned u, float& a, float& b) {
  a = __uint_as_float(u << 16);
  b = __uint_as_float(u & 0xFFFF0000u);
}

// ---------------- pack x: f32 -> bf16, 8 elems/thread ----------------
__global__ __launch_bounds__(256) void pack_x_kernel(const float* __restrict__ x,
                                                     ushort* __restrict__ xb) {
  int i = (blockIdx.x * 256 + threadIdx.x) * 8;
  float4 a = *(const float4*)(x + i);
  float4 b = *(const float4*)(x + i + 4);
  uint4 o;
  o.x = (unsigned)f2bf(a.x) | ((unsigned)f2bf(a.y) << 16);
  o.y = (unsigned)f2bf(a.z) | ((unsigned)f2bf(a.w) << 16);
  o.z = (unsigned)f2bf(b.x) | ((unsigned)f2bf(b.y) << 16);
  o.w = (unsigned)f2bf(b.z) | ((unsigned)f2bf(b.w) << 16);
  *(uint4*)(xb + i) = o;
}

// ---------------- pack weights transposed to bf16 ----------------
// blocks 0..767: Wq/Wk/Wv heads -> WqkvT[3072][1024]  (row n = s*1024+h*64+e, col = d)
// blocks 768..1023: Wp[1024][1024] -> WpT[1024][1024] (row n = out-dim col of Wp)
__global__ __launch_bounds__(256) void pack_w_kernel(const float* __restrict__ Wq,
                                                     const float* __restrict__ Wk,
                                                     const float* __restrict__ Wv,
                                                     const float* __restrict__ Wp,
                                                     ushort* __restrict__ WqkvT,
                                                     ushort* __restrict__ WpT) {
  __shared__ float tile[64][65];
  const int bid = blockIdx.x;
  const int tid = threadIdx.x;
  const int lr = tid >> 6;   // 0..3  (row-within-pass)
  const int lc = tid & 63;   // 0..63 (col)
  if (bid < 768) {
    const int s = bid >> 8;            // 0..2
    const int rem = bid & 255;
    const int h = rem >> 4;            // 0..15
    const int dt = rem & 15;           // 0..15 (64-row d tile)
    const float* W = (s == 0) ? Wq : (s == 1) ? Wk : Wv;
#pragma unroll
    for (int p = 0; p < 16; ++p) {
      int r = p * 4 + lr;  // d offset
      tile[r][lc] = W[(size_t)(h * 1024 + dt * 64 + r) * 64 + lc];
    }
    __syncthreads();
#pragma unroll
    for (int p = 0; p < 16; ++p) {
      int e = p * 4 + lr;  // output row offset
      float v = tile[lc][e];
      WqkvT[(size_t)(s * 1024 + h * 64 + e) * 1024 + dt * 64 + lc] = f2bf(v);
    }
  } else {
    const int t = bid - 768;
    const int rt = t >> 4, ct = t & 15;
#pragma unroll
    for (int p = 0; p < 16; ++p) {
      int r = p * 4 + lr;
      tile[r][lc] = Wp[(size_t)(rt * 64 + r) * 1024 + ct * 64 + lc];
    }
    __syncthreads();
#pragma unroll
    for (int p = 0; p < 16; ++p) {
      int c = p * 4 + lr;  // output row offset (Wp col)
      float v = tile[lc][c];
      WpT[(size_t)(ct * 64 + c) * 1024 + rt * 64 + lc] = f2bf(v);
    }
  }
}

// ---------------- bf16 MFMA GEMM: C[M,N] = A[M,K] * BT[N,K]^T ----------------
// 128x128 tile, BK=32, 4 waves (2x2), each wave 64x64 via 4x4 16x16x32 frags.
// OUT_MODE 0: bf16 C ; OUT_MODE 1: f32 C + bias
template <int OUT_MODE>
__global__ __launch_bounds__(256) void gemm_bt(const ushort* __restrict__ A,
                                               const ushort* __restrict__ BT,
                                               ushort* __restrict__ Cb,
                                               float* __restrict__ Cf,
                                               const float* __restrict__ bias,
                                               int M, int N, int K) {
  __shared__ ushort Al[128 * 32];
  __shared__ ushort Bl[128 * 32];
  const int tid = threadIdx.x;
  const int lane = tid & 63;
  const int wave = tid >> 6;
  const int wm = wave >> 1, wn = wave & 1;
  const int m0 = blockIdx.y * 128, n0 = blockIdx.x * 128;
  const int r16 = lane & 15, g = lane >> 4;
  f32x4 acc[4][4] = {};
  const int kTiles = K >> 5;
  const size_t ldb = (size_t)K * 2;  // row stride in bytes (A and BT both have K cols)
  for (int kt = 0; kt < kTiles; ++kt) {
    const int k0b = kt * 64;  // 32 bf16 = 64 bytes
    if (kt) __syncthreads();
#pragma unroll
    for (int p = 0; p < 2; ++p) {
      int lin = p * 4096 + tid * 16;  // byte offset within 8KB tile
      int row = lin >> 6;             // 64B per row
      int rb = lin & 63;
      *(uint4*)((char*)Al + lin) =
          *(const uint4*)((const char*)A + (size_t)(m0 + row) * ldb + k0b + rb);
      *(uint4*)((char*)Bl + lin) =
          *(const uint4*)((const char*)BT + (size_t)(n0 + row) * ldb + k0b + rb);
    }
    __syncthreads();
    short8 af[4], bfr[4];
#pragma unroll
    for (int i = 0; i < 4; ++i) {
      af[i] = *(const short8*)(Al + ((wm * 64 + i * 16 + r16) * 32 + g * 8));
      bfr[i] = *(const short8*)(Bl + ((wn * 64 + i * 16 + r16) * 32 + g * 8));
    }
#pragma unroll
    for (int mi = 0; mi < 4; ++mi)
#pragma unroll
      for (int ni = 0; ni < 4; ++ni)
        acc[mi][ni] =
            __builtin_amdgcn_mfma_f32_16x16x32_bf16(af[mi], bfr[ni], acc[mi][ni], 0, 0, 0);
  }
#pragma unroll
  for (int mi = 0; mi < 4; ++mi)
#pragma unroll
    for (int ni = 0; ni < 4; ++ni)
#pragma unroll
      for (int r = 0; r < 4; ++r) {
        int row = m0 + wm * 64 + mi * 16 + g * 4 + r;
        int col = n0 + wn * 64 + ni * 16 + r16;
        float v = acc[mi][ni][r];
        if (OUT_MODE == 0) {
          Cb[(size_t)row * N + col] = f2bf(v);
        } else {
          Cf[(size_t)row * N + col] = v + bias[col];
        }
      }
}

// ---------------- vector f32 causal flash attention ----------------
// grid (qt=8, h=16, b=4), 256 threads. Q tile = 256 rows. Lane owns 4 rows x 16 dims.
// No max-tracking: scores bounded (~|s|<10), p=exp(s) exact in f32; softmax is
// shift-invariant so this matches the reference.
__global__ __launch_bounds__(256) void attn_kernel(const ushort* __restrict__ QKV,
                                                   ushort* __restrict__ O) {
  const int qt = blockIdx.x, h = blockIdx.y, b = blockIdx.z;
  __shared__ float Kl[32 * 68];
  __shared__ float Vl[32 * 68];
  const int tid = threadIdx.x;
  const int seg = tid & 3;           // 16-dim segment
  const int rgrp = (tid >> 2) & 15;  // row group within wave
  const int wave = tid >> 6;
  const int grow = qt * 256 + wave * 64 + rgrp * 4;  // global q row base (4 rows)
  float q[4][16], o[4][16], l[4];
#pragma unroll
  for (int j = 0; j < 4; ++j) {
    l[j] = 0.f;
#pragma unroll
    for (int i = 0; i < 16; ++i) o[j][i] = 0.f;
  }
#pragma unroll
  for (int j = 0; j < 4; ++j) {
    const ushort* qp = QKV + ((size_t)(b * 2048 + grow + j) * 3072) + h * 64 + seg * 16;
    uint4 u0 = *(const uint4*)qp;
    uint4 u1 = *(const uint4*)(qp + 8);
    unpack2(u0.x, q[j][0], q[j][1]);  unpack2(u0.y, q[j][2], q[j][3]);
    unpack2(u0.z, q[j][4], q[j][5]);  unpack2(u0.w, q[j][6], q[j][7]);
    unpack2(u1.x, q[j][8], q[j][9]);  unpack2(u1.y, q[j][10], q[j][11]);
    unpack2(u1.z, q[j][12], q[j][13]); unpack2(u1.w, q[j][14], q[j][15]);
#pragma unroll
    for (int i = 0; i < 16; ++i) q[j][i] *= 0.125f;  // HS^-0.5 folded into q
  }
  const int nblk = qt * 8 + 8;  // key blocks of 32 up to causal limit
  const int skey = tid >> 3;
  const int se0 = (tid & 7) * 8;
  for (int blk = 0; blk < nblk; ++blk) {
    const int s0 = blk * 32;
    __syncthreads();
    {  // stage K,V block (bf16 -> f32 LDS, rows padded to 68)
      const ushort* kp = QKV + ((size_t)(b * 2048 + s0 + skey) * 3072) + 1024 + h * 64 + se0;
      uint4 ku = *(const uint4*)kp;
      uint4 vu = *(const uint4*)(kp + 1024);
      float kf[8], vf[8];
      unpack2(ku.x, kf[0], kf[1]); unpack2(ku.y, kf[2], kf[3]);
      unpack2(ku.z, kf[4], kf[5]); unpack2(ku.w, kf[6], kf[7]);
      unpack2(vu.x, vf[0], vf[1]); unpack2(vu.y, vf[2], vf[3]);
      unpack2(vu.z, vf[4], vf[5]); unpack2(vu.w, vf[6], vf[7]);
#pragma unroll
      for (int i = 0; i < 8; ++i) {
        Kl[skey * 68 + se0 + i] = kf[i];
        Vl[skey * 68 + se0 + i] = vf[i];
      }
    }
    __syncthreads();
#pragma unroll 2
    for (int s = 0; s < 32; ++s) {
      float kv[16];
      const float4* kr = (const float4*)&Kl[s * 68 + seg * 16];
      *(float4*)&kv[0] = kr[0];  *(float4*)&kv[4] = kr[1];
      *(float4*)&kv[8] = kr[2];  *(float4*)&kv[12] = kr[3];
      float p[4];
#pragma unroll
      for (int j = 0; j < 4; ++j) {
        float t = 0.f;
#pragma unroll
        for (int i = 0; i < 16; ++i) t = fmaf(q[j][i], kv[i], t);
        t += __shfl_xor(t, 1);
        t += __shfl_xor(t, 2);
        p[j] = t;
      }
      const int sg = s0 + s;
      float vv[16];
      const float4* vr = (const float4*)&Vl[s * 68 + seg * 16];
      *(float4*)&vv[0] = vr[0];  *(float4*)&vv[4] = vr[1];
      *(float4*)&vv[8] = vr[2];  *(float4*)&vv[12] = vr[3];
#pragma unroll
      for (int j = 0; j < 4; ++j) {
        float pj = __expf(p[j]);
        pj = (sg <= grow + j) ? pj : 0.f;
        l[j] += pj;
#pragma unroll
        for (int i = 0; i < 16; ++i) o[j][i] = fmaf(pj, vv[i], o[j][i]);
      }
    }
  }
#pragma unroll
  for (int j = 0; j < 4; ++j) {
    float inv = 1.f / l[j];
    uint4 w0, w1;
    w0.x = (unsigned)f2bf(o[j][0] * inv)  | ((unsigned)f2bf(o[j][1] * inv) << 16);
    w0.y = (unsigned)f2bf(o[j][2] * inv)  | ((unsigned)f2bf(o[j][3] * inv) << 16);
    w0.z = (unsigned)f2bf(o[j][4] * inv)  | ((unsigned)f2bf(o[j][5] * inv) << 16);
    w0.w = (unsigned)f2bf(o[j][6] * inv)  | ((unsigned)f2bf(o[j][7] * inv) << 16);
    w1.x = (unsigned)f2bf(o[j][8] * inv)  | ((unsigned)f2bf(o[j][9] * inv) << 16);
    w1.y = (unsigned)f2bf(o[j][10] * inv) | ((unsigned)f2bf(o[j][11] * inv) << 16);
    w1.z = (unsigned)f2bf(o[j][12] * inv) | ((unsigned)f2bf(o[j][13] * inv) << 16);
    w1.w = (unsigned)f2bf(o[j][14] * inv) | ((unsigned)f2bf(o[j][15] * inv) << 16);
    ushort* op = O + ((size_t)(b * 2048 + grow + j) * 1024) + h * 64 + seg * 16;
    *(uint4*)op = w0;
    *(uint4*)(op + 8) = w1;
  }
}

extern "C" void kernel_launch(void* const* d_in, const int* in_sizes, int n_in,
                              void* d_out, int out_size, void* d_ws, size_t ws_size,
                              hipStream_t stream) {
  const float* x = (const float*)d_in[0];
  const float* Wq = (const float*)d_in[1];
  const float* Wk = (const float*)d_in[2];
  const float* Wv = (const float*)d_in[3];
  const float* Wp = (const float*)d_in[4];
  const float* bp = (const float*)d_in[5];
  float* out = (float*)d_out;

  // workspace layout (ushort elements); total = 92.3 MB
  ushort* xb = (ushort*)d_ws;            // x as bf16            [8192,1024]
  ushort* WqkvT = xb + 8388608;          // packed W^T           [3072,1024]
  ushort* WpT = WqkvT + 3145728;         // Wp^T                 [1024,1024]
  ushort* QKV = WpT + 1048576;           // projections          [8192,3072]
  ushort* O = QKV + 25165824;            // attention out        [8192,1024]

  pack_x_kernel<<<4096, 256, 0, stream>>>(x, xb);
  pack_w_kernel<<<1024, 256, 0, stream>>>(Wq, Wk, Wv, Wp, WqkvT, WpT);
  // QKV projection: [8192,1024] x [1024,3072]
  gemm_bt<0><<<dim3(24, 64), 256, 0, stream>>>(xb, WqkvT, QKV, nullptr, nullptr,
                                               8192, 3072, 1024);
  // causal attention per (b,h), 256-row Q tiles
  attn_kernel<<<dim3(8, 16, 4), 256, 0, stream>>>(QKV, O);
  // output projection + bias: [8192,1024] x [1024,1024] -> f32
  gemm_bt<1><<<dim3(8, 64), 256, 0, stream>>>(O, WpT, nullptr, out, bp,
                                              8192, 1024, 1024);
}

// Round 2
// 237.635 us; speedup vs baseline: 4.9559x; 4.9559x over previous
//
#include <hip/hip_runtime.h>
#include <stdint.h>

// Problem constants: B=4, T=2048, D=1024, H=16, HS=64
typedef __attribute__((ext_vector_type(8))) short short8;
typedef __attribute__((ext_vector_type(4))) float f32x4;
typedef __attribute__((ext_vector_type(16))) float f32x16;

__device__ __forceinline__ unsigned short f2bf(float f) {
  unsigned u = __float_as_uint(f);
  u = u + 0x7FFFu + ((u >> 16) & 1u);  // RNE
  return (unsigned short)(u >> 16);
}
__device__ __forceinline__ unsigned cvtpk_bf16(float lo, float hi) {
  unsigned r;
  asm("v_cvt_pk_bf16_f32 %0, %1, %2" : "=v"(r) : "v"(lo), "v"(hi));
  return r;
}

// ---------------- pack x: f32 -> bf16, 8 elems/thread ----------------
__global__ __launch_bounds__(256) void pack_x_kernel(const float* __restrict__ x,
                                                     ushort* __restrict__ xb) {
  int i = (blockIdx.x * 256 + threadIdx.x) * 8;
  float4 a = *(const float4*)(x + i);
  float4 b = *(const float4*)(x + i + 4);
  uint4 o;
  o.x = (unsigned)f2bf(a.x) | ((unsigned)f2bf(a.y) << 16);
  o.y = (unsigned)f2bf(a.z) | ((unsigned)f2bf(a.w) << 16);
  o.z = (unsigned)f2bf(b.x) | ((unsigned)f2bf(b.y) << 16);
  o.w = (unsigned)f2bf(b.z) | ((unsigned)f2bf(b.w) << 16);
  *(uint4*)(xb + i) = o;
}

// ---------------- pack weights transposed to bf16 ----------------
__global__ __launch_bounds__(256) void pack_w_kernel(const float* __restrict__ Wq,
                                                     const float* __restrict__ Wk,
                                                     const float* __restrict__ Wv,
                                                     const float* __restrict__ Wp,
                                                     ushort* __restrict__ WqkvT,
                                                     ushort* __restrict__ WpT) {
  __shared__ float tile[64][65];
  const int bid = blockIdx.x;
  const int tid = threadIdx.x;
  const int lr = tid >> 6;   // 0..3
  const int lc = tid & 63;   // 0..63
  if (bid < 768) {
    const int s = bid >> 8;
    const int rem = bid & 255;
    const int h = rem >> 4;
    const int dt = rem & 15;
    const float* W = (s == 0) ? Wq : (s == 1) ? Wk : Wv;
#pragma unroll
    for (int p = 0; p < 16; ++p) {
      int r = p * 4 + lr;
      tile[r][lc] = W[(size_t)(h * 1024 + dt * 64 + r) * 64 + lc];
    }
    __syncthreads();
#pragma unroll
    for (int p = 0; p < 16; ++p) {
      int e = p * 4 + lr;
      float v = tile[lc][e];
      WqkvT[(size_t)(s * 1024 + h * 64 + e) * 1024 + dt * 64 + lc] = f2bf(v);
    }
  } else {
    const int t = bid - 768;
    const int rt = t >> 4, ct = t & 15;
#pragma unroll
    for (int p = 0; p < 16; ++p) {
      int r = p * 4 + lr;
      tile[r][lc] = Wp[(size_t)(rt * 64 + r) * 1024 + ct * 64 + lc];
    }
    __syncthreads();
#pragma unroll
    for (int p = 0; p < 16; ++p) {
      int c = p * 4 + lr;
      float v = tile[lc][c];
      WpT[(size_t)(ct * 64 + c) * 1024 + rt * 64 + lc] = f2bf(v);
    }
  }
}

// ---------------- bf16 MFMA GEMM: C[M,N] = A[M,K] * BT[N,K]^T ----------------
template <int OUT_MODE>
__global__ __launch_bounds__(256) void gemm_bt(const ushort* __restrict__ A,
                                               const ushort* __restrict__ BT,
                                               ushort* __restrict__ Cb,
                                               float* __restrict__ Cf,
                                               const float* __restrict__ bias,
                                               int M, int N, int K) {
  __shared__ ushort Al[128 * 32];
  __shared__ ushort Bl[128 * 32];
  const int tid = threadIdx.x;
  const int lane = tid & 63;
  const int wave = tid >> 6;
  const int wm = wave >> 1, wn = wave & 1;
  const int m0 = blockIdx.y * 128, n0 = blockIdx.x * 128;
  const int r16 = lane & 15, g = lane >> 4;
  f32x4 acc[4][4] = {};
  const int kTiles = K >> 5;
  const size_t ldb = (size_t)K * 2;
  for (int kt = 0; kt < kTiles; ++kt) {
    const int k0b = kt * 64;
    if (kt) __syncthreads();
#pragma unroll
    for (int p = 0; p < 2; ++p) {
      int lin = p * 4096 + tid * 16;
      int row = lin >> 6;
      int rb = lin & 63;
      *(uint4*)((char*)Al + lin) =
          *(const uint4*)((const char*)A + (size_t)(m0 + row) * ldb + k0b + rb);
      *(uint4*)((char*)Bl + lin) =
          *(const uint4*)((const char*)BT + (size_t)(n0 + row) * ldb + k0b + rb);
    }
    __syncthreads();
    short8 af[4], bfr[4];
#pragma unroll
    for (int i = 0; i < 4; ++i) {
      af[i] = *(const short8*)(Al + ((wm * 64 + i * 16 + r16) * 32 + g * 8));
      bfr[i] = *(const short8*)(Bl + ((wn * 64 + i * 16 + r16) * 32 + g * 8));
    }
#pragma unroll
    for (int mi = 0; mi < 4; ++mi)
#pragma unroll
      for (int ni = 0; ni < 4; ++ni)
        acc[mi][ni] =
            __builtin_amdgcn_mfma_f32_16x16x32_bf16(af[mi], bfr[ni], acc[mi][ni], 0, 0, 0);
  }
#pragma unroll
  for (int mi = 0; mi < 4; ++mi)
#pragma unroll
    for (int ni = 0; ni < 4; ++ni)
#pragma unroll
      for (int r = 0; r < 4; ++r) {
        int row = m0 + wm * 64 + mi * 16 + g * 4 + r;
        int col = n0 + wn * 64 + ni * 16 + r16;
        float v = acc[mi][ni][r];
        if (OUT_MODE == 0) {
          Cb[(size_t)row * N + col] = f2bf(v);
        } else {
          Cf[(size_t)row * N + col] = v + bias[col];
        }
      }
}

// ---------------- MFMA causal flash attention (swapped QK^T, 32x32) ----------------
// grid (qt=16, h=16, b=4), 4 waves x 32 q-rows, KVBLK=64.
// S^T = mfma(K,Q): lane owns qrow = lane&31; key(r) = (r&3)+8*(r>>2)+4*hi.
// Softmax is in-lane (no max-tracking; scores ~N(0,1), validated round 1).
// P -> PV A-frag via v_cvt_pk_bf16_f32 + v_permlane32_swap_b32.
__global__ __launch_bounds__(256) void attn_mfma_kernel(const ushort* __restrict__ QKV,
                                                        ushort* __restrict__ O) {
  const int qt = 15 - (int)blockIdx.x;  // heavy causal tiles launch first
  const int h = blockIdx.y, b = blockIdx.z;
  __shared__ __align__(16) ushort Kl[64 * 64];  // K rows, XOR-swizzled
  __shared__ __align__(16) ushort VT[64 * 64];  // V transposed [dim][key], swizzled
  const int tid = threadIdx.x;
  const int lane = tid & 63;
  const int wave = tid >> 6;
  const int lo5 = lane & 31;
  const int hi = lane >> 5;
  const int qbase = qt * 128 + wave * 32;

  // Q frags (B operand): qf[dc] = Q[qbase+lo5][dc*16 + hi*8 .. +7]
  short8 qf[4];
  {
    const ushort* qp = QKV + ((size_t)(b * 2048 + qbase + lo5) * 3072) + h * 64 + hi * 8;
#pragma unroll
    for (int dc = 0; dc < 4; ++dc) qf[dc] = *(const short8*)(qp + dc * 16);
  }

  f32x16 o0 = {}, o1 = {};  // O dims 0-31, 32-63: row=qrow(r,hi), col=dim=lo5
  float l_acc = 0.f;

  const int nblk = qt * 2 + 2;
  for (int blk = 0; blk < nblk; ++blk) {
    const int s0 = blk * 64;
    __syncthreads();
    {  // stage K: 64 keys x 128B rows, swizzled, ds_write_b128
      const int key = tid & 63, ch = tid >> 6;
      const ushort* kp = QKV + ((size_t)(b * 2048 + s0 + key) * 3072) + 1024 + h * 64 + ch * 16;
      uint4 k0 = *(const uint4*)kp;
      uint4 k1 = *(const uint4*)(kp + 8);
      char* dst = (char*)Kl + key * 128;
      const int sw = (key & 7) << 4;
      *(uint4*)(dst + ((ch * 32) ^ sw)) = k0;
      *(uint4*)(dst + ((ch * 32 + 16) ^ sw)) = k1;
    }
    {  // stage V transposed: thread owns key pair (2k,2k+1) x 8 dims -> 8 b32 writes
      const int kp2 = (tid & 31) * 2;
      const int dg = tid >> 5;
      const ushort* vp = QKV + ((size_t)(b * 2048 + s0 + kp2) * 3072) + 2048 + h * 64 + dg * 8;
      uint4 v0 = *(const uint4*)vp;
      uint4 v1 = *(const uint4*)(vp + 3072);
      const ushort* e0 = (const ushort*)&v0;
      const ushort* e1 = (const ushort*)&v1;
#pragma unroll
      for (int j = 0; j < 8; ++j) {
        const int row = dg * 8 + j;
        *(unsigned*)((char*)VT + row * 128 + ((kp2 * 2) ^ ((row & 7) << 4))) =
            (unsigned)e0[j] | ((unsigned)e1[j] << 16);
      }
    }
    __syncthreads();

#pragma unroll
    for (int g2 = 0; g2 < 2; ++g2) {
      // S^T = K . Q^T over 4 dim-chunks of 16
      f32x16 s_acc = {};
      const int krow = g2 * 32 + lo5;
      const char* ksrc = (const char*)Kl + krow * 128;
      const int ksw = (krow & 7) << 4;
#pragma unroll
      for (int dc = 0; dc < 4; ++dc) {
        short8 kf = *(const short8*)(ksrc + ((dc * 32 + hi * 16) ^ ksw));
        s_acc = __builtin_amdgcn_mfma_f32_32x32x16_bf16(kf, qf[dc], s_acc, 0, 0, 0);
      }
      // p = exp(s * HS^-0.5), causal-masked; l accumulates in-lane
      float p[16];
      const int qg = qbase + lo5;
      const int ksg = s0 + g2 * 32 + 4 * hi;
#pragma unroll
      for (int r = 0; r < 16; ++r) {
        const int key_g = ksg + (r & 3) + 8 * (r >> 2);
        float pv = __expf(s_acc[r] * 0.125f);
        pv = (key_g <= qg) ? pv : 0.f;
        p[r] = pv;
        l_acc += pv;
      }
      // P -> A-frags (bf16) via cvt_pk + permlane32_swap; PV over 2 key-chunks
#pragma unroll
      for (int kc = 0; kc < 2; ++kc) {
        unsigned w0 = cvtpk_bf16(p[kc * 8 + 0], p[kc * 8 + 1]);
        unsigned w2 = cvtpk_bf16(p[kc * 8 + 4], p[kc * 8 + 5]);
        unsigned w1 = cvtpk_bf16(p[kc * 8 + 2], p[kc * 8 + 3]);
        unsigned w3 = cvtpk_bf16(p[kc * 8 + 6], p[kc * 8 + 7]);
        asm("v_permlane32_swap_b32 %0, %1" : "+v"(w0), "+v"(w2));
        asm("v_permlane32_swap_b32 %0, %1" : "+v"(w1), "+v"(w3));
        uint4 paw;
        paw.x = w0; paw.y = w1; paw.z = w2; paw.w = w3;
        short8 pa = *(short8*)&paw;
        const int kb = (g2 * 32 + kc * 16 + hi * 8) * 2;  // key byte offset in VT row
        {
          const int vrow = lo5;
          short8 vf = *(const short8*)((const char*)VT + vrow * 128 + (kb ^ ((vrow & 7) << 4)));
          o0 = __builtin_amdgcn_mfma_f32_32x32x16_bf16(pa, vf, o0, 0, 0, 0);
        }
        {
          const int vrow = 32 + lo5;
          short8 vf = *(const short8*)((const char*)VT + vrow * 128 + (kb ^ ((vrow & 7) << 4)));
          o1 = __builtin_amdgcn_mfma_f32_32x32x16_bf16(pa, vf, o1, 0, 0, 0);
        }
      }
    }
  }
  // lane and lane^32 hold complementary key-halves of the same qrow's l
  l_acc += __shfl_xor(l_acc, 32);
  const float linv = 1.f / l_acc;
#pragma unroll
  for (int r = 0; r < 16; ++r) {
    const int qr = (r & 3) + 8 * (r >> 2) + 4 * hi;
    const float li = __shfl(linv, qr);
    ushort* ob = O + ((size_t)(b * 2048 + qbase + qr) * 1024) + h * 64 + lo5;
    ob[0] = f2bf(o0[r] * li);
    ob[32] = f2bf(o1[r] * li);
  }
}

extern "C" void kernel_launch(void* const* d_in, const int* in_sizes, int n_in,
                              void* d_out, int out_size, void* d_ws, size_t ws_size,
                              hipStream_t stream) {
  const float* x = (const float*)d_in[0];
  const float* Wq = (const float*)d_in[1];
  const float* Wk = (const float*)d_in[2];
  const float* Wv = (const float*)d_in[3];
  const float* Wp = (const float*)d_in[4];
  const float* bp = (const float*)d_in[5];
  float* out = (float*)d_out;

  ushort* xb = (ushort*)d_ws;            // [8192,1024]
  ushort* WqkvT = xb + 8388608;          // [3072,1024]
  ushort* WpT = WqkvT + 3145728;         // [1024,1024]
  ushort* QKV = WpT + 1048576;           // [8192,3072]
  ushort* O = QKV + 25165824;            // [8192,1024]

  pack_x_kernel<<<4096, 256, 0, stream>>>(x, xb);
  pack_w_kernel<<<1024, 256, 0, stream>>>(Wq, Wk, Wv, Wp, WqkvT, WpT);
  gemm_bt<0><<<dim3(24, 64), 256, 0, stream>>>(xb, WqkvT, QKV, nullptr, nullptr,
                                               8192, 3072, 1024);
  attn_mfma_kernel<<<dim3(16, 16, 4), 256, 0, stream>>>(QKV, O);
  gemm_bt<1><<<dim3(8, 64), 256, 0, stream>>>(O, WpT, nullptr, out, bp,
                                              8192, 1024, 1024);
}

// Round 3
// 188.286 us; speedup vs baseline: 6.2548x; 1.2621x over previous
//
#include <hip/hip_runtime.h>
#include <stdint.h>

// Problem constants: B=4, T=2048, D=1024, H=16, HS=64
typedef __attribute__((ext_vector_type(8))) short short8;
typedef __attribute__((ext_vector_type(4))) float f32x4;
typedef __attribute__((ext_vector_type(16))) float f32x16;

__device__ __forceinline__ unsigned short f2bf(float f) {
  unsigned u = __float_as_uint(f);
  u = u + 0x7FFFu + ((u >> 16) & 1u);  // RNE
  return (unsigned short)(u >> 16);
}
__device__ __forceinline__ unsigned cvtpk_bf16(float lo, float hi) {
  unsigned r;
  asm("v_cvt_pk_bf16_f32 %0, %1, %2" : "=v"(r) : "v"(lo), "v"(hi));
  return r;
}
// async global->LDS, 16B per lane; lptr must be wave-uniform (HW adds lane*16)
__device__ __forceinline__ void gl2lds16(const void* g, void* l) {
  __builtin_amdgcn_global_load_lds(
      (const __attribute__((address_space(1))) void*)(uintptr_t)g,
      (__attribute__((address_space(3))) void*)(uintptr_t)l, 16, 0, 0);
}

// ---------------- pack x: f32 -> bf16, 8 elems/thread ----------------
__global__ __launch_bounds__(256) void pack_x_kernel(const float* __restrict__ x,
                                                     ushort* __restrict__ xb) {
  int i = (blockIdx.x * 256 + threadIdx.x) * 8;
  float4 a = *(const float4*)(x + i);
  float4 b = *(const float4*)(x + i + 4);
  uint4 o;
  o.x = (unsigned)f2bf(a.x) | ((unsigned)f2bf(a.y) << 16);
  o.y = (unsigned)f2bf(a.z) | ((unsigned)f2bf(a.w) << 16);
  o.z = (unsigned)f2bf(b.x) | ((unsigned)f2bf(b.y) << 16);
  o.w = (unsigned)f2bf(b.z) | ((unsigned)f2bf(b.w) << 16);
  *(uint4*)(xb + i) = o;
}

// ---------------- pack weights transposed to bf16 ----------------
__global__ __launch_bounds__(256) void pack_w_kernel(const float* __restrict__ Wq,
                                                     const float* __restrict__ Wk,
                                                     const float* __restrict__ Wv,
                                                     const float* __restrict__ Wp,
                                                     ushort* __restrict__ WqkvT,
                                                     ushort* __restrict__ WpT) {
  __shared__ float tile[64][65];
  const int bid = blockIdx.x;
  const int tid = threadIdx.x;
  const int lr = tid >> 6;   // 0..3
  const int lc = tid & 63;   // 0..63
  if (bid < 768) {
    const int s = bid >> 8;
    const int rem = bid & 255;
    const int h = rem >> 4;
    const int dt = rem & 15;
    const float* W = (s == 0) ? Wq : (s == 1) ? Wk : Wv;
#pragma unroll
    for (int p = 0; p < 16; ++p) {
      int r = p * 4 + lr;
      tile[r][lc] = W[(size_t)(h * 1024 + dt * 64 + r) * 64 + lc];
    }
    __syncthreads();
#pragma unroll
    for (int p = 0; p < 16; ++p) {
      int e = p * 4 + lr;
      float v = tile[lc][e];
      WqkvT[(size_t)(s * 1024 + h * 64 + e) * 1024 + dt * 64 + lc] = f2bf(v);
    }
  } else {
    const int t = bid - 768;
    const int rt = t >> 4, ct = t & 15;
#pragma unroll
    for (int p = 0; p < 16; ++p) {
      int r = p * 4 + lr;
      tile[r][lc] = Wp[(size_t)(rt * 64 + r) * 1024 + ct * 64 + lc];
    }
    __syncthreads();
#pragma unroll
    for (int p = 0; p < 16; ++p) {
      int c = p * 4 + lr;
      float v = tile[lc][c];
      WpT[(size_t)(ct * 64 + c) * 1024 + rt * 64 + lc] = f2bf(v);
    }
  }
}

// ---------------- bf16 MFMA GEMM: C[M,N] = A[M,K] * BT[N,K]^T ----------------
// m97 structure: 128x128 tile, BK=32, global_load_lds width=16, XCD swizzle.
template <int OUT_MODE>
__global__ __launch_bounds__(256) void gemm_bt(const ushort* __restrict__ A,
                                               const ushort* __restrict__ BT,
                                               ushort* __restrict__ Cb,
                                               float* __restrict__ Cf,
                                               const float* __restrict__ bias,
                                               int M, int N, int K) {
  __shared__ __align__(16) ushort Al[128 * 32];
  __shared__ __align__(16) ushort Bl[128 * 32];
  const int tid = threadIdx.x;
  const int lane = tid & 63;
  const int wave = tid >> 6;
  const int wm = wave >> 1, wn = wave & 1;
  // XCD-chunked swizzle (nwg % 8 == 0 in all our launches)
  const int nbx = gridDim.x;
  const int nwg = nbx * gridDim.y;
  int wg = blockIdx.y * nbx + blockIdx.x;
  wg = (wg & 7) * (nwg >> 3) + (wg >> 3);
  const int m0 = (wg / nbx) * 128, n0 = (wg % nbx) * 128;
  const int r16 = lane & 15, g = lane >> 4;
  f32x4 acc[4][4] = {};
  const int kTiles = K >> 5;
  const size_t ldb = (size_t)K * 2;  // row stride in bytes
  // staging geometry: issue p in {0,1}; row = p*64 + tid/4, col-byte = (tid&3)*16
  const int srow = tid >> 2;
  const int srb = (tid & 3) * 16;
  const char* a_src = (const char*)A + (size_t)(m0 + srow) * ldb + srb;
  const char* b_src = (const char*)BT + (size_t)(n0 + srow) * ldb + srb;
  char* a_dst = (char*)Al + wave * 1024;
  char* b_dst = (char*)Bl + wave * 1024;
  for (int kt = 0; kt < kTiles; ++kt) {
    const int k0b = kt * 64;
    if (kt) __syncthreads();
    gl2lds16(a_src + k0b, a_dst);
    gl2lds16(a_src + (size_t)64 * ldb + k0b, a_dst + 4096);
    gl2lds16(b_src + k0b, b_dst);
    gl2lds16(b_src + (size_t)64 * ldb + k0b, b_dst + 4096);
    __syncthreads();
    short8 af[4], bfr[4];
#pragma unroll
    for (int i = 0; i < 4; ++i) {
      af[i] = *(const short8*)(Al + ((wm * 64 + i * 16 + r16) * 32 + g * 8));
      bfr[i] = *(const short8*)(Bl + ((wn * 64 + i * 16 + r16) * 32 + g * 8));
    }
#pragma unroll
    for (int mi = 0; mi < 4; ++mi)
#pragma unroll
      for (int ni = 0; ni < 4; ++ni)
        acc[mi][ni] =
            __builtin_amdgcn_mfma_f32_16x16x32_bf16(af[mi], bfr[ni], acc[mi][ni], 0, 0, 0);
  }
#pragma unroll
  for (int mi = 0; mi < 4; ++mi)
#pragma unroll
    for (int ni = 0; ni < 4; ++ni)
#pragma unroll
      for (int r = 0; r < 4; ++r) {
        int row = m0 + wm * 64 + mi * 16 + g * 4 + r;
        int col = n0 + wn * 64 + ni * 16 + r16;
        float v = acc[mi][ni][r];
        if (OUT_MODE == 0) {
          Cb[(size_t)row * N + col] = f2bf(v);
        } else {
          Cf[(size_t)row * N + col] = v + bias[col];
        }
      }
}

// ---------------- MFMA causal flash attention (swapped QK^T, 32x32) ----------------
// grid (8,16,4); each WG processes Q-tiles (15-qtA) and (qtA) -> uniform 34
// key-blocks per WG (causal pairing load-balance). 4 waves x 32 q-rows.
// S^T = mfma(K,Q): lane owns qrow = lane&31; key(r) = (r&3)+8*(r>>2)+4*hi.
__global__ __launch_bounds__(256) void attn_mfma_kernel(const ushort* __restrict__ QKV,
                                                        ushort* __restrict__ O) {
  // XCD-chunked swizzle over flattened 512-WG grid
  int flat = blockIdx.z * 128 + blockIdx.y * 8 + blockIdx.x;
  flat = (flat & 7) * 64 + (flat >> 3);
  const int qtA = flat & 7;
  const int h = (flat >> 3) & 15;
  const int b = flat >> 7;
  __shared__ __align__(16) ushort Kl[64 * 64];  // K rows, XOR-swizzled
  __shared__ __align__(16) ushort VT[64 * 64];  // V transposed [dim][key], swizzled
  const int tid = threadIdx.x;
  const int lane = tid & 63;
  const int wave = tid >> 6;
  const int lo5 = lane & 31;
  const int hi = lane >> 5;

#pragma unroll
  for (int ph = 0; ph < 2; ++ph) {
    const int qt = ph ? qtA : (15 - qtA);
    const int qbase = qt * 128 + wave * 32;

    short8 qf[4];
    {
      const ushort* qp = QKV + ((size_t)(b * 2048 + qbase + lo5) * 3072) + h * 64 + hi * 8;
#pragma unroll
      for (int dc = 0; dc < 4; ++dc) qf[dc] = *(const short8*)(qp + dc * 16);
    }

    f32x16 o0 = {}, o1 = {};
    float l_acc = 0.f;

    const int nblk = qt * 2 + 2;
    for (int blk = 0; blk < nblk; ++blk) {
      const int s0 = blk * 64;
      __syncthreads();
      {  // stage K: 64 keys x 128B rows, swizzled
        const int key = tid & 63, ch = tid >> 6;
        const ushort* kp =
            QKV + ((size_t)(b * 2048 + s0 + key) * 3072) + 1024 + h * 64 + ch * 16;
        uint4 k0 = *(const uint4*)kp;
        uint4 k1 = *(const uint4*)(kp + 8);
        char* dst = (char*)Kl + key * 128;
        const int sw = (key & 7) << 4;
        *(uint4*)(dst + ((ch * 32) ^ sw)) = k0;
        *(uint4*)(dst + ((ch * 32 + 16) ^ sw)) = k1;
      }
      {  // stage V transposed: thread owns key pair (2k,2k+1) x 8 dims
        const int kp2 = (tid & 31) * 2;
        const int dg = tid >> 5;
        const ushort* vp =
            QKV + ((size_t)(b * 2048 + s0 + kp2) * 3072) + 2048 + h * 64 + dg * 8;
        uint4 v0 = *(const uint4*)vp;
        uint4 v1 = *(const uint4*)(vp + 3072);
        const ushort* e0 = (const ushort*)&v0;
        const ushort* e1 = (const ushort*)&v1;
#pragma unroll
        for (int j = 0; j < 8; ++j) {
          const int row = dg * 8 + j;
          *(unsigned*)((char*)VT + row * 128 + ((kp2 * 2) ^ ((row & 7) << 4))) =
              (unsigned)e0[j] | ((unsigned)e1[j] << 16);
        }
      }
      __syncthreads();

#pragma unroll
      for (int g2 = 0; g2 < 2; ++g2) {
        f32x16 s_acc = {};
        const int krow = g2 * 32 + lo5;
        const char* ksrc = (const char*)Kl + krow * 128;
        const int ksw = (krow & 7) << 4;
#pragma unroll
        for (int dc = 0; dc < 4; ++dc) {
          short8 kf = *(const short8*)(ksrc + ((dc * 32 + hi * 16) ^ ksw));
          s_acc = __builtin_amdgcn_mfma_f32_32x32x16_bf16(kf, qf[dc], s_acc, 0, 0, 0);
        }
        float p[16];
        const int qg = qbase + lo5;
        const int ksg = s0 + g2 * 32 + 4 * hi;
#pragma unroll
        for (int r = 0; r < 16; ++r) {
          const int key_g = ksg + (r & 3) + 8 * (r >> 2);
          float pv = __expf(s_acc[r] * 0.125f);
          pv = (key_g <= qg) ? pv : 0.f;
          p[r] = pv;
          l_acc += pv;
        }
#pragma unroll
        for (int kc = 0; kc < 2; ++kc) {
          unsigned w0 = cvtpk_bf16(p[kc * 8 + 0], p[kc * 8 + 1]);
          unsigned w2 = cvtpk_bf16(p[kc * 8 + 4], p[kc * 8 + 5]);
          unsigned w1 = cvtpk_bf16(p[kc * 8 + 2], p[kc * 8 + 3]);
          unsigned w3 = cvtpk_bf16(p[kc * 8 + 6], p[kc * 8 + 7]);
          asm("v_permlane32_swap_b32 %0, %1" : "+v"(w0), "+v"(w2));
          asm("v_permlane32_swap_b32 %0, %1" : "+v"(w1), "+v"(w3));
          uint4 paw;
          paw.x = w0; paw.y = w1; paw.z = w2; paw.w = w3;
          short8 pa = *(short8*)&paw;
          const int kb = (g2 * 32 + kc * 16 + hi * 8) * 2;
          {
            const int vrow = lo5;
            short8 vf =
                *(const short8*)((const char*)VT + vrow * 128 + (kb ^ ((vrow & 7) << 4)));
            o0 = __builtin_amdgcn_mfma_f32_32x32x16_bf16(pa, vf, o0, 0, 0, 0);
          }
          {
            const int vrow = 32 + lo5;
            short8 vf =
                *(const short8*)((const char*)VT + vrow * 128 + (kb ^ ((vrow & 7) << 4)));
            o1 = __builtin_amdgcn_mfma_f32_32x32x16_bf16(pa, vf, o1, 0, 0, 0);
          }
        }
      }
    }
    l_acc += __shfl_xor(l_acc, 32);
    const float linv = 1.f / l_acc;
#pragma unroll
    for (int r = 0; r < 16; ++r) {
      const int qr = (r & 3) + 8 * (r >> 2) + 4 * hi;
      const float li = __shfl(linv, qr);
      ushort* ob = O + ((size_t)(b * 2048 + qbase + qr) * 1024) + h * 64 + lo5;
      ob[0] = f2bf(o0[r] * li);
      ob[32] = f2bf(o1[r] * li);
    }
  }
}

extern "C" void kernel_launch(void* const* d_in, const int* in_sizes, int n_in,
                              void* d_out, int out_size, void* d_ws, size_t ws_size,
                              hipStream_t stream) {
  const float* x = (const float*)d_in[0];
  const float* Wq = (const float*)d_in[1];
  const float* Wk = (const float*)d_in[2];
  const float* Wv = (const float*)d_in[3];
  const float* Wp = (const float*)d_in[4];
  const float* bp = (const float*)d_in[5];
  float* out = (float*)d_out;

  ushort* xb = (ushort*)d_ws;            // [8192,1024]
  ushort* WqkvT = xb + 8388608;          // [3072,1024]
  ushort* WpT = WqkvT + 3145728;         // [1024,1024]
  ushort* QKV = WpT + 1048576;           // [8192,3072]
  ushort* O = QKV + 25165824;            // [8192,1024]

  pack_x_kernel<<<4096, 256, 0, stream>>>(x, xb);
  pack_w_kernel<<<1024, 256, 0, stream>>>(Wq, Wk, Wv, Wp, WqkvT, WpT);
  gemm_bt<0><<<dim3(24, 64), 256, 0, stream>>>(xb, WqkvT, QKV, nullptr, nullptr,
                                               8192, 3072, 1024);
  attn_mfma_kernel<<<dim3(8, 16, 4), 256, 0, stream>>>(QKV, O);
  gemm_bt<1><<<dim3(8, 64), 256, 0, stream>>>(O, WpT, nullptr, out, bp,
                                              8192, 1024, 1024);
}

// Round 5
// 171.614 us; speedup vs baseline: 6.8624x; 1.0971x over previous
//
#include <hip/hip_runtime.h>
#include <stdint.h>

// Problem constants: B=4, T=2048, D=1024, H=16, HS=64
typedef __attribute__((ext_vector_type(8))) short short8;
typedef __attribute__((ext_vector_type(4))) float f32x4;
typedef __attribute__((ext_vector_type(16))) float f32x16;

__device__ __forceinline__ unsigned short f2bf(float f) {
  unsigned u = __float_as_uint(f);
  u = u + 0x7FFFu + ((u >> 16) & 1u);  // RNE
  return (unsigned short)(u >> 16);
}
__device__ __forceinline__ unsigned cvtpk_bf16(float lo, float hi) {
  unsigned r;
  asm("v_cvt_pk_bf16_f32 %0, %1, %2" : "=v"(r) : "v"(lo), "v"(hi));
  return r;
}
__device__ __forceinline__ float fast_exp2(float x) {
#if __has_builtin(__builtin_amdgcn_exp2f)
  return __builtin_amdgcn_exp2f(x);
#else
  return exp2f(x);
#endif
}
// async global->LDS, 16B per lane; lds ptr wave-uniform (HW adds lane*16)
__device__ __forceinline__ void gl2lds16(const void* g, void* l) {
  __builtin_amdgcn_global_load_lds(
      (const __attribute__((address_space(1))) void*)(uintptr_t)g,
      (__attribute__((address_space(3))) void*)(uintptr_t)l, 16, 0, 0);
}

// ---------------- pack x: f32 -> bf16, 8 elems/thread ----------------
__global__ __launch_bounds__(256) void pack_x_kernel(const float* __restrict__ x,
                                                     ushort* __restrict__ xb) {
  int i = (blockIdx.x * 256 + threadIdx.x) * 8;
  float4 a = *(const float4*)(x + i);
  float4 b = *(const float4*)(x + i + 4);
  uint4 o;
  o.x = (unsigned)f2bf(a.x) | ((unsigned)f2bf(a.y) << 16);
  o.y = (unsigned)f2bf(a.z) | ((unsigned)f2bf(a.w) << 16);
  o.z = (unsigned)f2bf(b.x) | ((unsigned)f2bf(b.y) << 16);
  o.w = (unsigned)f2bf(b.z) | ((unsigned)f2bf(b.w) << 16);
  *(uint4*)(xb + i) = o;
}

// ---------------- pack weights transposed to bf16 ----------------
// Wq is pre-scaled by HS^-0.5 * log2(e) so attention scores are in exp2 units.
__global__ __launch_bounds__(256) void pack_w_kernel(const float* __restrict__ Wq,
                                                     const float* __restrict__ Wk,
                                                     const float* __restrict__ Wv,
                                                     const float* __restrict__ Wp,
                                                     ushort* __restrict__ WqkvT,
                                                     ushort* __restrict__ WpT) {
  __shared__ float tile[64][65];
  const int bid = blockIdx.x;
  const int tid = threadIdx.x;
  const int lr = tid >> 6;   // 0..3
  const int lc = tid & 63;   // 0..63
  if (bid < 768) {
    const int s = bid >> 8;
    const int rem = bid & 255;
    const int h = rem >> 4;
    const int dt = rem & 15;
    const float* W = (s == 0) ? Wq : (s == 1) ? Wk : Wv;
    const float scale = (s == 0) ? 0.18033688011f : 1.0f;  // 0.125 * log2(e)
#pragma unroll
    for (int p = 0; p < 16; ++p) {
      int r = p * 4 + lr;
      tile[r][lc] = W[(size_t)(h * 1024 + dt * 64 + r) * 64 + lc];
    }
    __syncthreads();
#pragma unroll
    for (int p = 0; p < 16; ++p) {
      int e = p * 4 + lr;
      float v = tile[lc][e] * scale;
      WqkvT[(size_t)(s * 1024 + h * 64 + e) * 1024 + dt * 64 + lc] = f2bf(v);
    }
  } else {
    const int t = bid - 768;
    const int rt = t >> 4, ct = t & 15;
#pragma unroll
    for (int p = 0; p < 16; ++p) {
      int r = p * 4 + lr;
      tile[r][lc] = Wp[(size_t)(rt * 64 + r) * 1024 + ct * 64 + lc];
    }
    __syncthreads();
#pragma unroll
    for (int p = 0; p < 16; ++p) {
      int c = p * 4 + lr;
      float v = tile[lc][c];
      WpT[(size_t)(ct * 64 + c) * 1024 + rt * 64 + lc] = f2bf(v);
    }
  }
}

// ---------------- bf16 MFMA GEMM: C[M,N] = A[M,K] * BT[N,K]^T ----------------
// m97 structure: 128x128 tile, BK=32, global_load_lds width=16, XCD swizzle.
template <int OUT_MODE>
__global__ __launch_bounds__(256) void gemm_bt(const ushort* __restrict__ A,
                                               const ushort* __restrict__ BT,
                                               ushort* __restrict__ Cb,
                                               float* __restrict__ Cf,
                                               const float* __restrict__ bias,
                                               int M, int N, int K) {
  __shared__ __align__(16) ushort Al[128 * 32];
  __shared__ __align__(16) ushort Bl[128 * 32];
  const int tid = threadIdx.x;
  const int lane = tid & 63;
  const int wave = tid >> 6;
  const int wm = wave >> 1, wn = wave & 1;
  const int nbx = gridDim.x;
  const int nwg = nbx * gridDim.y;
  int wg = blockIdx.y * nbx + blockIdx.x;
  wg = (wg & 7) * (nwg >> 3) + (wg >> 3);
  const int m0 = (wg / nbx) * 128, n0 = (wg % nbx) * 128;
  const int r16 = lane & 15, g = lane >> 4;
  f32x4 acc[4][4] = {};
  const int kTiles = K >> 5;
  const size_t ldb = (size_t)K * 2;
  const int srow = tid >> 2;
  const int srb = (tid & 3) * 16;
  const char* a_src = (const char*)A + (size_t)(m0 + srow) * ldb + srb;
  const char* b_src = (const char*)BT + (size_t)(n0 + srow) * ldb + srb;
  char* a_dst = (char*)Al + wave * 1024;
  char* b_dst = (char*)Bl + wave * 1024;
  for (int kt = 0; kt < kTiles; ++kt) {
    const int k0b = kt * 64;
    if (kt) __syncthreads();
    gl2lds16(a_src + k0b, a_dst);
    gl2lds16(a_src + (size_t)64 * ldb + k0b, a_dst + 4096);
    gl2lds16(b_src + k0b, b_dst);
    gl2lds16(b_src + (size_t)64 * ldb + k0b, b_dst + 4096);
    __syncthreads();
    short8 af[4], bfr[4];
#pragma unroll
    for (int i = 0; i < 4; ++i) {
      af[i] = *(const short8*)(Al + ((wm * 64 + i * 16 + r16) * 32 + g * 8));
      bfr[i] = *(const short8*)(Bl + ((wn * 64 + i * 16 + r16) * 32 + g * 8));
    }
#pragma unroll
    for (int mi = 0; mi < 4; ++mi)
#pragma unroll
      for (int ni = 0; ni < 4; ++ni)
        acc[mi][ni] =
            __builtin_amdgcn_mfma_f32_16x16x32_bf16(af[mi], bfr[ni], acc[mi][ni], 0, 0, 0);
  }
#pragma unroll
  for (int mi = 0; mi < 4; ++mi)
#pragma unroll
    for (int ni = 0; ni < 4; ++ni)
#pragma unroll
      for (int r = 0; r < 4; ++r) {
        int row = m0 + wm * 64 + mi * 16 + g * 4 + r;
        int col = n0 + wn * 64 + ni * 16 + r16;
        float v = acc[mi][ni][r];
        if (OUT_MODE == 0) {
          Cb[(size_t)row * N + col] = f2bf(v);
        } else {
          Cf[(size_t)row * N + col] = v + bias[col];
        }
      }
}

// ---------------- MFMA causal flash attention (swapped QK^T, 32x32) ----------------
// grid (8,16,4); each WG does Q-tiles (15-qtA) and (qtA): uniform 34 key-blocks.
// r3-proven two-barrier skeleton, single-buffered K/V (race-free by construction):
//   barrier A (top) -> stage writes (V ds_write from prefetched regs; K gl2lds
//   with pre-swizzled source) -> barrier B -> V(blk+1) reg loads + compute.
// Scores in exp2 units (Wq pre-scaled); fully-masked g2 skipped; mask only on
// the straddling g2 (wave-uniform branch).
__global__ __launch_bounds__(256) void attn_mfma_kernel(const ushort* __restrict__ QKV,
                                                        ushort* __restrict__ O) {
  int flat = blockIdx.z * 128 + blockIdx.y * 8 + blockIdx.x;
  flat = (flat & 7) * 64 + (flat >> 3);
  const int qtA = flat & 7;
  const int h = (flat >> 3) & 15;
  const int b = flat >> 7;
  __shared__ __align__(16) ushort Kl[64 * 64];  // K rows, XOR-swizzled content
  __shared__ __align__(16) ushort VT[64 * 64];  // V transposed [dim][key], swizzled
  const int tid = threadIdx.x;
  const int lane = tid & 63;
  const int wave = tid >> 6;
  const int lo5 = lane & 31;
  const int hi = lane >> 5;

  // K gl2lds geometry: lane covers LDS linear = wave*2048 + i*1024 + lane*16
  //   -> key = wave*16 + i*8 + (lane>>3), col-byte = (lane&7)*16, pre-swizzled src
  const int k_key0 = wave * 16 + (lane >> 3);
  const int k_key1 = k_key0 + 8;
  const int ksrc_off0 = ((lane & 7) * 16) ^ ((k_key0 & 7) << 4);
  const int ksrc_off1 = ((lane & 7) * 16) ^ ((k_key1 & 7) << 4);
  const char* kgbase = (const char*)(QKV + ((size_t)b * 2048) * 3072 + 1024 + h * 64);
  // V reg-stage: thread owns key pair (kp2, kp2+1) x dims dg*8..dg*8+7
  const int kp2 = (tid & 31) * 2;
  const int dg = tid >> 5;
  const char* vgbase = (const char*)(QKV + ((size_t)b * 2048) * 3072 + 2048 + h * 64 + dg * 8);

#pragma unroll
  for (int ph = 0; ph < 2; ++ph) {
    const int qt = ph ? qtA : (15 - qtA);
    const int qbase = qt * 128 + wave * 32;
    const int qg = qbase + lo5;

    short8 qf[4];
    {
      const ushort* qp = QKV + ((size_t)(b * 2048 + qbase + lo5) * 3072) + h * 64 + hi * 8;
#pragma unroll
      for (int dc = 0; dc < 4; ++dc) qf[dc] = *(const short8*)(qp + dc * 16);
    }

    f32x16 o0 = {}, o1 = {};
    float l_acc = 0.f;
    const int nblk = qt * 2 + 2;

    // prologue: issue V(0) register loads
    uint4 nv0, nv1;
    {
      const char* vp = vgbase + (size_t)kp2 * 6144;
      nv0 = *(const uint4*)(vp);
      nv1 = *(const uint4*)(vp + 6144);
    }

    for (int blk = 0; blk < nblk; ++blk) {
      const int s0 = blk * 64;
      __syncthreads();  // A: all waves done reading Kl/VT from previous block
      {                 // stage V(blk) from prefetched regs (transposed, swizzled)
        const ushort* e0 = (const ushort*)&nv0;
        const ushort* e1 = (const ushort*)&nv1;
#pragma unroll
        for (int j = 0; j < 8; ++j) {
          const int row = dg * 8 + j;
          *(unsigned*)((char*)VT + row * 128 + ((kp2 * 2) ^ ((row & 7) << 4))) =
              (unsigned)e0[j] | ((unsigned)e1[j] << 16);
        }
      }
      // stage K(blk) via async global->LDS (linear dest, pre-swizzled source)
      gl2lds16(kgbase + (size_t)(s0 + k_key0) * 6144 + ksrc_off0, (char*)Kl + wave * 2048);
      gl2lds16(kgbase + (size_t)(s0 + k_key1) * 6144 + ksrc_off1,
               (char*)Kl + wave * 2048 + 1024);
      __syncthreads();  // B: staging visible (vmcnt+lgkmcnt drained by all waves)

      if (blk + 1 < nblk) {  // prefetch V(blk+1) into regs during compute
        const char* vp = vgbase + (size_t)(s0 + 64 + kp2) * 6144;
        nv0 = *(const uint4*)(vp);
        nv1 = *(const uint4*)(vp + 6144);
      }

#pragma unroll
      for (int g2 = 0; g2 < 2; ++g2) {
        const int ks = s0 + g2 * 32;
        if (ks > qbase + 31) continue;  // fully masked (wave-uniform)
        f32x16 s_acc = {};
        const int krow = g2 * 32 + lo5;
        const char* ksrc = (const char*)Kl + krow * 128;
        const int ksw = (krow & 7) << 4;
#pragma unroll
        for (int dc = 0; dc < 4; ++dc) {
          short8 kf = *(const short8*)(ksrc + ((dc * 32 + hi * 16) ^ ksw));
          s_acc = __builtin_amdgcn_mfma_f32_32x32x16_bf16(kf, qf[dc], s_acc, 0, 0, 0);
        }
        float p[16];
        if (ks + 31 > qbase) {  // straddling diagonal: mask (wave-uniform branch)
          const int ksg = ks + 4 * hi;
#pragma unroll
          for (int r = 0; r < 16; ++r) {
            const int key_g = ksg + (r & 3) + 8 * (r >> 2);
            float pv = fast_exp2(s_acc[r]);
            pv = (key_g <= qg) ? pv : 0.f;
            p[r] = pv;
            l_acc += pv;
          }
        } else {  // fully valid: no mask
#pragma unroll
          for (int r = 0; r < 16; ++r) {
            float pv = fast_exp2(s_acc[r]);
            p[r] = pv;
            l_acc += pv;
          }
        }
#pragma unroll
        for (int kc = 0; kc < 2; ++kc) {
          unsigned w0 = cvtpk_bf16(p[kc * 8 + 0], p[kc * 8 + 1]);
          unsigned w2 = cvtpk_bf16(p[kc * 8 + 4], p[kc * 8 + 5]);
          unsigned w1 = cvtpk_bf16(p[kc * 8 + 2], p[kc * 8 + 3]);
          unsigned w3 = cvtpk_bf16(p[kc * 8 + 6], p[kc * 8 + 7]);
          asm("v_permlane32_swap_b32 %0, %1" : "+v"(w0), "+v"(w2));
          asm("v_permlane32_swap_b32 %0, %1" : "+v"(w1), "+v"(w3));
          uint4 paw;
          paw.x = w0; paw.y = w1; paw.z = w2; paw.w = w3;
          short8 pa = *(short8*)&paw;
          const int kb = (g2 * 32 + kc * 16 + hi * 8) * 2;
          {
            const int vrow = lo5;
            short8 vf =
                *(const short8*)((const char*)VT + vrow * 128 + (kb ^ ((vrow & 7) << 4)));
            o0 = __builtin_amdgcn_mfma_f32_32x32x16_bf16(pa, vf, o0, 0, 0, 0);
          }
          {
            const int vrow = 32 + lo5;
            short8 vf =
                *(const short8*)((const char*)VT + vrow * 128 + (kb ^ ((vrow & 7) << 4)));
            o1 = __builtin_amdgcn_mfma_f32_32x32x16_bf16(pa, vf, o1, 0, 0, 0);
          }
        }
      }
    }

    l_acc += __shfl_xor(l_acc, 32);
    const float linv = 1.f / l_acc;
#pragma unroll
    for (int r = 0; r < 16; ++r) {
      const int qr = (r & 3) + 8 * (r >> 2) + 4 * hi;
      const float li = __shfl(linv, qr);
      ushort* ob = O + ((size_t)(b * 2048 + qbase + qr) * 1024) + h * 64 + lo5;
      ob[0] = f2bf(o0[r] * li);
      ob[32] = f2bf(o1[r] * li);
    }
  }
}

extern "C" void kernel_launch(void* const* d_in, const int* in_sizes, int n_in,
                              void* d_out, int out_size, void* d_ws, size_t ws_size,
                              hipStream_t stream) {
  const float* x = (const float*)d_in[0];
  const float* Wq = (const float*)d_in[1];
  const float* Wk = (const float*)d_in[2];
  const float* Wv = (const float*)d_in[3];
  const float* Wp = (const float*)d_in[4];
  const float* bp = (const float*)d_in[5];
  float* out = (float*)d_out;

  ushort* xb = (ushort*)d_ws;            // [8192,1024]
  ushort* WqkvT = xb + 8388608;          // [3072,1024]
  ushort* WpT = WqkvT + 3145728;         // [1024,1024]
  ushort* QKV = WpT + 1048576;           // [8192,3072]
  ushort* O = QKV + 25165824;            // [8192,1024]

  pack_x_kernel<<<4096, 256, 0, stream>>>(x, xb);
  pack_w_kernel<<<1024, 256, 0, stream>>>(Wq, Wk, Wv, Wp, WqkvT, WpT);
  gemm_bt<0><<<dim3(24, 64), 256, 0, stream>>>(xb, WqkvT, QKV, nullptr, nullptr,
                                               8192, 3072, 1024);
  attn_mfma_kernel<<<dim3(8, 16, 4), 256, 0, stream>>>(QKV, O);
  gemm_bt<1><<<dim3(8, 64), 256, 0, stream>>>(O, WpT, nullptr, out, bp,
                                              8192, 1024, 1024);
}

// Round 6
// 166.897 us; speedup vs baseline: 7.0564x; 1.0283x over previous
//
#include <hip/hip_runtime.h>
#include <stdint.h>

// Problem constants: B=4, T=2048, D=1024, H=16, HS=64
typedef __attribute__((ext_vector_type(8))) short short8;
typedef __attribute__((ext_vector_type(4))) float f32x4;
typedef __attribute__((ext_vector_type(16))) float f32x16;

__device__ __forceinline__ unsigned short f2bf(float f) {
  unsigned u = __float_as_uint(f);
  u = u + 0x7FFFu + ((u >> 16) & 1u);  // RNE
  return (unsigned short)(u >> 16);
}
__device__ __forceinline__ unsigned cvtpk_bf16(float lo, float hi) {
  unsigned r;
  asm("v_cvt_pk_bf16_f32 %0, %1, %2" : "=v"(r) : "v"(lo), "v"(hi));
  return r;
}
__device__ __forceinline__ float fast_exp2(float x) {
#if __has_builtin(__builtin_amdgcn_exp2f)
  return __builtin_amdgcn_exp2f(x);
#else
  return exp2f(x);
#endif
}
// async global->LDS, 16B per lane; lds ptr wave-uniform (HW adds lane*16)
__device__ __forceinline__ void gl2lds16(const void* g, void* l) {
  __builtin_amdgcn_global_load_lds(
      (const __attribute__((address_space(1))) void*)(uintptr_t)g,
      (__attribute__((address_space(3))) void*)(uintptr_t)l, 16, 0, 0);
}

// ---------------- fused pack: x -> bf16; weights -> transposed bf16 ----------------
// blocks 0..4095: x
// blocks 4096..4863: Wq/Wk/Wv -> WqkvT[3072][1024] (Wq pre-scaled by 0.125*log2e)
// blocks 4864..5119: Wp -> WpT[1024][1024]
__global__ __launch_bounds__(256) void pack_all_kernel(const float* __restrict__ x,
                                                       const float* __restrict__ Wq,
                                                       const float* __restrict__ Wk,
                                                       const float* __restrict__ Wv,
                                                       const float* __restrict__ Wp,
                                                       ushort* __restrict__ xb,
                                                       ushort* __restrict__ WqkvT,
                                                       ushort* __restrict__ WpT) {
  __shared__ float tile[64][65];
  const int bid0 = blockIdx.x;
  const int tid = threadIdx.x;
  if (bid0 < 4096) {
    int i = (bid0 * 256 + tid) * 8;
    float4 a = *(const float4*)(x + i);
    float4 b = *(const float4*)(x + i + 4);
    uint4 o;
    o.x = (unsigned)f2bf(a.x) | ((unsigned)f2bf(a.y) << 16);
    o.y = (unsigned)f2bf(a.z) | ((unsigned)f2bf(a.w) << 16);
    o.z = (unsigned)f2bf(b.x) | ((unsigned)f2bf(b.y) << 16);
    o.w = (unsigned)f2bf(b.z) | ((unsigned)f2bf(b.w) << 16);
    *(uint4*)(xb + i) = o;
    return;
  }
  const int bid = bid0 - 4096;
  const int lr = tid >> 6;   // 0..3
  const int lc = tid & 63;   // 0..63
  if (bid < 768) {
    const int s = bid >> 8;
    const int rem = bid & 255;
    const int h = rem >> 4;
    const int dt = rem & 15;
    const float* W = (s == 0) ? Wq : (s == 1) ? Wk : Wv;
    const float scale = (s == 0) ? 0.18033688011f : 1.0f;  // 0.125 * log2(e)
#pragma unroll
    for (int p = 0; p < 16; ++p) {
      int r = p * 4 + lr;
      tile[r][lc] = W[(size_t)(h * 1024 + dt * 64 + r) * 64 + lc];
    }
    __syncthreads();
#pragma unroll
    for (int p = 0; p < 16; ++p) {
      int e = p * 4 + lr;
      float v = tile[lc][e] * scale;
      WqkvT[(size_t)(s * 1024 + h * 64 + e) * 1024 + dt * 64 + lc] = f2bf(v);
    }
  } else {
    const int t = bid - 768;
    const int rt = t >> 4, ct = t & 15;
#pragma unroll
    for (int p = 0; p < 16; ++p) {
      int r = p * 4 + lr;
      tile[r][lc] = Wp[(size_t)(rt * 64 + r) * 1024 + ct * 64 + lc];
    }
    __syncthreads();
#pragma unroll
    for (int p = 0; p < 16; ++p) {
      int c = p * 4 + lr;
      float v = tile[lc][c];
      WpT[(size_t)(ct * 64 + c) * 1024 + rt * 64 + lc] = f2bf(v);
    }
  }
}

// ---------------- bf16 MFMA GEMM: C[M,N] = A[M,K] * BT[N,K]^T ----------------
// 128x128 tile, BK=32, ring-3 LDS (48KB) counted-vmcnt pipeline:
//   iter t: stage tile t+2 -> slot (t+2)%3, compute slot t%3,
//           s_waitcnt vmcnt(4) (t+1 landed, t+2 in flight), raw s_barrier.
// Slot (t+2)%3 last read in iter t-1 (done before its barrier) -> race-free.
// LDS swizzled: col16 ^= (row&3)<<4 on read; source pre-swizzled (linear dest).
template <int OUT_MODE>
__global__ __launch_bounds__(256) void gemm_bt(const ushort* __restrict__ A,
                                               const ushort* __restrict__ BT,
                                               ushort* __restrict__ Cb,
                                               float* __restrict__ Cf,
                                               const float* __restrict__ bias,
                                               int M, int N, int K) {
  __shared__ __align__(16) ushort Al[3][128 * 32];
  __shared__ __align__(16) ushort Bl[3][128 * 32];
  const int tid = threadIdx.x;
  const int lane = tid & 63;
  const int wave = tid >> 6;
  const int wm = wave >> 1, wn = wave & 1;
  const int nbx = gridDim.x;
  const int nwg = nbx * gridDim.y;
  int wg = blockIdx.y * nbx + blockIdx.x;
  wg = (wg & 7) * (nwg >> 3) + (wg >> 3);
  const int m0 = (wg / nbx) * 128, n0 = (wg % nbx) * 128;
  const int r16 = lane & 15, g = lane >> 4;
  f32x4 acc[4][4] = {};
  const int kTiles = K >> 5;
  const size_t ldb = (size_t)K * 2;
  // staging: row = p*64 + tid/4, col16 = (tid&3); source pre-swizzled
  const int srow = tid >> 2;
  const int scolsw = ((tid & 3) * 16) ^ ((srow & 3) << 4);
  const char* a_src = (const char*)A + (size_t)(m0 + srow) * ldb + scolsw;
  const char* b_src = (const char*)BT + (size_t)(n0 + srow) * ldb + scolsw;
  const size_t half = (size_t)64 * ldb;
  char* a_d0 = (char*)&Al[0][0] + wave * 1024;
  char* b_d0 = (char*)&Bl[0][0] + wave * 1024;

#define STAGE(kt, slot)                                        \
  {                                                            \
    const int k0b = (kt) * 64;                                 \
    gl2lds16(a_src + k0b, a_d0 + (slot)*8192);                 \
    gl2lds16(a_src + half + k0b, a_d0 + (slot)*8192 + 4096);   \
    gl2lds16(b_src + k0b, b_d0 + (slot)*8192);                 \
    gl2lds16(b_src + half + k0b, b_d0 + (slot)*8192 + 4096);   \
  }

  STAGE(0, 0);
  STAGE(1, 1);
  asm volatile("s_waitcnt vmcnt(4)" ::: "memory");
  __builtin_amdgcn_s_barrier();

  int slot = 0;
  const int swf = (r16 & 3) << 4;  // frag-read swizzle (row&3 == r16&3)
  for (int kt = 0; kt < kTiles; ++kt) {
    const int nslot = (slot == 0) ? 2 : slot - 1;  // (slot+2)%3
    if (kt + 2 < kTiles) STAGE(kt + 2, nslot);
    const char* Ab = (const char*)&Al[slot][0];
    const char* Bb = (const char*)&Bl[slot][0];
    short8 af[4], bfr[4];
#pragma unroll
    for (int i = 0; i < 4; ++i) {
      af[i] = *(const short8*)(Ab + (wm * 64 + i * 16 + r16) * 64 + ((g * 16) ^ swf));
      bfr[i] = *(const short8*)(Bb + (wn * 64 + i * 16 + r16) * 64 + ((g * 16) ^ swf));
    }
#pragma unroll
    for (int mi = 0; mi < 4; ++mi)
#pragma unroll
      for (int ni = 0; ni < 4; ++ni)
        acc[mi][ni] =
            __builtin_amdgcn_mfma_f32_16x16x32_bf16(af[mi], bfr[ni], acc[mi][ni], 0, 0, 0);
    if (kt + 2 < kTiles) {
      asm volatile("s_waitcnt vmcnt(4)" ::: "memory");
    } else {
      asm volatile("s_waitcnt vmcnt(0)" ::: "memory");
    }
    __builtin_amdgcn_s_barrier();
    slot = (slot == 2) ? 0 : slot + 1;
  }
#undef STAGE

#pragma unroll
  for (int mi = 0; mi < 4; ++mi)
#pragma unroll
    for (int ni = 0; ni < 4; ++ni)
#pragma unroll
      for (int r = 0; r < 4; ++r) {
        int row = m0 + wm * 64 + mi * 16 + g * 4 + r;
        int col = n0 + wn * 64 + ni * 16 + r16;
        float v = acc[mi][ni][r];
        if (OUT_MODE == 0) {
          Cb[(size_t)row * N + col] = f2bf(v);
        } else {
          Cf[(size_t)row * N + col] = v + bias[col];
        }
      }
}

// ---------------- MFMA causal flash attention (swapped QK^T, 32x32) ----------------
// grid (8,16,4); each WG does Q-tiles (15-qtA) and (qtA): uniform 34 key-blocks.
// Two-barrier skeleton (race-free), single-buffered K/V.
// l accumulated via mfma(pa, ones): lacc[r] row-aligned with o0/o1 -> no shuffles.
__global__ __launch_bounds__(256) void attn_mfma_kernel(const ushort* __restrict__ QKV,
                                                        ushort* __restrict__ O) {
  int flat = blockIdx.z * 128 + blockIdx.y * 8 + blockIdx.x;
  flat = (flat & 7) * 64 + (flat >> 3);
  const int qtA = flat & 7;
  const int h = (flat >> 3) & 15;
  const int b = flat >> 7;
  __shared__ __align__(16) ushort Kl[64 * 64];
  __shared__ __align__(16) ushort VT[64 * 64];
  const int tid = threadIdx.x;
  const int lane = tid & 63;
  const int wave = tid >> 6;
  const int lo5 = lane & 31;
  const int hi = lane >> 5;

  short8 ones;
#pragma unroll
  for (int i = 0; i < 8; ++i) ones[i] = (short)0x3F80;  // bf16 1.0

  const int k_key0 = wave * 16 + (lane >> 3);
  const int k_key1 = k_key0 + 8;
  const int ksrc_off0 = ((lane & 7) * 16) ^ ((k_key0 & 7) << 4);
  const int ksrc_off1 = ((lane & 7) * 16) ^ ((k_key1 & 7) << 4);
  const char* kgbase = (const char*)(QKV + ((size_t)b * 2048) * 3072 + 1024 + h * 64);
  const int kp2 = (tid & 31) * 2;
  const int dg = tid >> 5;
  const char* vgbase = (const char*)(QKV + ((size_t)b * 2048) * 3072 + 2048 + h * 64 + dg * 8);

#pragma unroll
  for (int ph = 0; ph < 2; ++ph) {
    const int qt = ph ? qtA : (15 - qtA);
    const int qbase = qt * 128 + wave * 32;
    const int qg = qbase + lo5;

    short8 qf[4];
    {
      const ushort* qp = QKV + ((size_t)(b * 2048 + qbase + lo5) * 3072) + h * 64 + hi * 8;
#pragma unroll
      for (int dc = 0; dc < 4; ++dc) qf[dc] = *(const short8*)(qp + dc * 16);
    }

    f32x16 o0 = {}, o1 = {}, lacc = {};
    const int nblk = qt * 2 + 2;

    uint4 nv0, nv1;
    {
      const char* vp = vgbase + (size_t)kp2 * 6144;
      nv0 = *(const uint4*)(vp);
      nv1 = *(const uint4*)(vp + 6144);
    }

    for (int blk = 0; blk < nblk; ++blk) {
      const int s0 = blk * 64;
      __syncthreads();  // A: all waves done reading Kl/VT from previous block
      {                 // stage V(blk) from prefetched regs (transposed, swizzled)
        const ushort* e0 = (const ushort*)&nv0;
        const ushort* e1 = (const ushort*)&nv1;
#pragma unroll
        for (int j = 0; j < 8; ++j) {
          const int row = dg * 8 + j;
          *(unsigned*)((char*)VT + row * 128 + ((kp2 * 2) ^ ((row & 7) << 4))) =
              (unsigned)e0[j] | ((unsigned)e1[j] << 16);
        }
      }
      gl2lds16(kgbase + (size_t)(s0 + k_key0) * 6144 + ksrc_off0, (char*)Kl + wave * 2048);
      gl2lds16(kgbase + (size_t)(s0 + k_key1) * 6144 + ksrc_off1,
               (char*)Kl + wave * 2048 + 1024);
      __syncthreads();  // B: staging visible

      if (blk + 1 < nblk) {
        const char* vp = vgbase + (size_t)(s0 + 64 + kp2) * 6144;
        nv0 = *(const uint4*)(vp);
        nv1 = *(const uint4*)(vp + 6144);
      }

#pragma unroll
      for (int g2 = 0; g2 < 2; ++g2) {
        const int ks = s0 + g2 * 32;
        if (ks > qbase + 31) continue;  // fully masked (wave-uniform)
        f32x16 s_acc = {};
        const int krow = g2 * 32 + lo5;
        const char* ksrc = (const char*)Kl + krow * 128;
        const int ksw = (krow & 7) << 4;
#pragma unroll
        for (int dc = 0; dc < 4; ++dc) {
          short8 kf = *(const short8*)(ksrc + ((dc * 32 + hi * 16) ^ ksw));
          s_acc = __builtin_amdgcn_mfma_f32_32x32x16_bf16(kf, qf[dc], s_acc, 0, 0, 0);
        }
        float p[16];
        if (ks + 31 > qbase) {  // straddling diagonal
          const int ksg = ks + 4 * hi;
#pragma unroll
          for (int r = 0; r < 16; ++r) {
            const int key_g = ksg + (r & 3) + 8 * (r >> 2);
            float pv = fast_exp2(s_acc[r]);
            p[r] = (key_g <= qg) ? pv : 0.f;
          }
        } else {
#pragma unroll
          for (int r = 0; r < 16; ++r) p[r] = fast_exp2(s_acc[r]);
        }
#pragma unroll
        for (int kc = 0; kc < 2; ++kc) {
          unsigned w0 = cvtpk_bf16(p[kc * 8 + 0], p[kc * 8 + 1]);
          unsigned w2 = cvtpk_bf16(p[kc * 8 + 4], p[kc * 8 + 5]);
          unsigned w1 = cvtpk_bf16(p[kc * 8 + 2], p[kc * 8 + 3]);
          unsigned w3 = cvtpk_bf16(p[kc * 8 + 6], p[kc * 8 + 7]);
          asm("v_permlane32_swap_b32 %0, %1" : "+v"(w0), "+v"(w2));
          asm("v_permlane32_swap_b32 %0, %1" : "+v"(w1), "+v"(w3));
          uint4 paw;
          paw.x = w0; paw.y = w1; paw.z = w2; paw.w = w3;
          short8 pa = *(short8*)&paw;
          const int kb = (g2 * 32 + kc * 16 + hi * 8) * 2;
          lacc = __builtin_amdgcn_mfma_f32_32x32x16_bf16(pa, ones, lacc, 0, 0, 0);
          {
            const int vrow = lo5;
            short8 vf =
                *(const short8*)((const char*)VT + vrow * 128 + (kb ^ ((vrow & 7) << 4)));
            o0 = __builtin_amdgcn_mfma_f32_32x32x16_bf16(pa, vf, o0, 0, 0, 0);
          }
          {
            const int vrow = 32 + lo5;
            short8 vf =
                *(const short8*)((const char*)VT + vrow * 128 + (kb ^ ((vrow & 7) << 4)));
            o1 = __builtin_amdgcn_mfma_f32_32x32x16_bf16(pa, vf, o1, 0, 0, 0);
          }
        }
      }
    }

#pragma unroll
    for (int r = 0; r < 16; ++r) {
      const int qr = (r & 3) + 8 * (r >> 2) + 4 * hi;
      const float li = 1.f / lacc[r];
      ushort* ob = O + ((size_t)(b * 2048 + qbase + qr) * 1024) + h * 64 + lo5;
      ob[0] = f2bf(o0[r] * li);
      ob[32] = f2bf(o1[r] * li);
    }
  }
}

extern "C" void kernel_launch(void* const* d_in, const int* in_sizes, int n_in,
                              void* d_out, int out_size, void* d_ws, size_t ws_size,
                              hipStream_t stream) {
  const float* x = (const float*)d_in[0];
  const float* Wq = (const float*)d_in[1];
  const float* Wk = (const float*)d_in[2];
  const float* Wv = (const float*)d_in[3];
  const float* Wp = (const float*)d_in[4];
  const float* bp = (const float*)d_in[5];
  float* out = (float*)d_out;

  ushort* xb = (ushort*)d_ws;            // [8192,1024]
  ushort* WqkvT = xb + 8388608;          // [3072,1024]
  ushort* WpT = WqkvT + 3145728;         // [1024,1024]
  ushort* QKV = WpT + 1048576;           // [8192,3072]
  ushort* O = QKV + 25165824;            // [8192,1024]

  pack_all_kernel<<<5120, 256, 0, stream>>>(x, Wq, Wk, Wv, Wp, xb, WqkvT, WpT);
  gemm_bt<0><<<dim3(24, 64), 256, 0, stream>>>(xb, WqkvT, QKV, nullptr, nullptr,
                                               8192, 3072, 1024);
  attn_mfma_kernel<<<dim3(8, 16, 4), 256, 0, stream>>>(QKV, O);
  gemm_bt<1><<<dim3(8, 64), 256, 0, stream>>>(O, WpT, nullptr, out, bp,
                                              8192, 1024, 1024);
}

// Round 7
// 164.760 us; speedup vs baseline: 7.1479x; 1.0130x over previous
//
#include <hip/hip_runtime.h>
#include <stdint.h>

// Problem constants: B=4, T=2048, D=1024, H=16, HS=64
typedef __attribute__((ext_vector_type(8))) short short8;
typedef __attribute__((ext_vector_type(4))) float f32x4;
typedef __attribute__((ext_vector_type(16))) float f32x16;

__device__ __forceinline__ unsigned short f2bf(float f) {
  unsigned u = __float_as_uint(f);
  u = u + 0x7FFFu + ((u >> 16) & 1u);  // RNE
  return (unsigned short)(u >> 16);
}
__device__ __forceinline__ unsigned cvtpk_bf16(float lo, float hi) {
  unsigned r;
  asm("v_cvt_pk_bf16_f32 %0, %1, %2" : "=v"(r) : "v"(lo), "v"(hi));
  return r;
}
__device__ __forceinline__ float fast_exp2(float x) {
#if __has_builtin(__builtin_amdgcn_exp2f)
  return __builtin_amdgcn_exp2f(x);
#else
  return exp2f(x);
#endif
}
// async global->LDS, 16B per lane; lds ptr wave-uniform (HW adds lane*16)
__device__ __forceinline__ void gl2lds16(const void* g, void* l) {
  __builtin_amdgcn_global_load_lds(
      (const __attribute__((address_space(1))) void*)(uintptr_t)g,
      (__attribute__((address_space(3))) void*)(uintptr_t)l, 16, 0, 0);
}

// ---------------- fused pack: x -> bf16; weights -> transposed bf16 ----------------
__global__ __launch_bounds__(256) void pack_all_kernel(const float* __restrict__ x,
                                                       const float* __restrict__ Wq,
                                                       const float* __restrict__ Wk,
                                                       const float* __restrict__ Wv,
                                                       const float* __restrict__ Wp,
                                                       ushort* __restrict__ xb,
                                                       ushort* __restrict__ WqkvT,
                                                       ushort* __restrict__ WpT) {
  __shared__ float tile[64][65];
  const int bid0 = blockIdx.x;
  const int tid = threadIdx.x;
  if (bid0 < 4096) {
    int i = (bid0 * 256 + tid) * 8;
    float4 a = *(const float4*)(x + i);
    float4 b = *(const float4*)(x + i + 4);
    uint4 o;
    o.x = (unsigned)f2bf(a.x) | ((unsigned)f2bf(a.y) << 16);
    o.y = (unsigned)f2bf(a.z) | ((unsigned)f2bf(a.w) << 16);
    o.z = (unsigned)f2bf(b.x) | ((unsigned)f2bf(b.y) << 16);
    o.w = (unsigned)f2bf(b.z) | ((unsigned)f2bf(b.w) << 16);
    *(uint4*)(xb + i) = o;
    return;
  }
  const int bid = bid0 - 4096;
  const int lr = tid >> 6;   // 0..3
  const int lc = tid & 63;   // 0..63
  if (bid < 768) {
    const int s = bid >> 8;
    const int rem = bid & 255;
    const int h = rem >> 4;
    const int dt = rem & 15;
    const float* W = (s == 0) ? Wq : (s == 1) ? Wk : Wv;
    const float scale = (s == 0) ? 0.18033688011f : 1.0f;  // 0.125 * log2(e)
#pragma unroll
    for (int p = 0; p < 16; ++p) {
      int r = p * 4 + lr;
      tile[r][lc] = W[(size_t)(h * 1024 + dt * 64 + r) * 64 + lc];
    }
    __syncthreads();
#pragma unroll
    for (int p = 0; p < 16; ++p) {
      int e = p * 4 + lr;
      float v = tile[lc][e] * scale;
      WqkvT[(size_t)(s * 1024 + h * 64 + e) * 1024 + dt * 64 + lc] = f2bf(v);
    }
  } else {
    const int t = bid - 768;
    const int rt = t >> 4, ct = t & 15;
#pragma unroll
    for (int p = 0; p < 16; ++p) {
      int r = p * 4 + lr;
      tile[r][lc] = Wp[(size_t)(rt * 64 + r) * 1024 + ct * 64 + lc];
    }
    __syncthreads();
#pragma unroll
    for (int p = 0; p < 16; ++p) {
      int c = p * 4 + lr;
      float v = tile[lc][c];
      WpT[(size_t)(ct * 64 + c) * 1024 + rt * 64 + lc] = f2bf(v);
    }
  }
}

// ---------------- bf16 MFMA GEMM: C[M,N] = A[M,K] * BT[N,K]^T ----------------
// 128x128 tile, BK=64 (128B LDS rows), single-buffer 2-barrier skeleton (r5-proven).
// Row-XOR swizzle (byte ^= (row&7)<<4): pre-swizzled gl2lds source + XOR frag read
// (the attn-proven involution) -> conflict-lite ds_read_b128.
template <int OUT_MODE>
__global__ __launch_bounds__(256) void gemm_bt(const ushort* __restrict__ A,
                                               const ushort* __restrict__ BT,
                                               ushort* __restrict__ Cb,
                                               float* __restrict__ Cf,
                                               const float* __restrict__ bias,
                                               int M, int N, int K) {
  __shared__ __align__(16) ushort Al[128 * 64];
  __shared__ __align__(16) ushort Bl[128 * 64];
  const int tid = threadIdx.x;
  const int lane = tid & 63;
  const int wave = tid >> 6;
  const int wm = wave >> 1, wn = wave & 1;
  const int nbx = gridDim.x;
  const int nwg = nbx * gridDim.y;
  int wg = blockIdx.y * nbx + blockIdx.x;
  wg = (wg & 7) * (nwg >> 3) + (wg >> 3);
  const int m0 = (wg / nbx) * 128, n0 = (wg % nbx) * 128;
  const int r16 = lane & 15, g = lane >> 4;
  f32x4 acc[4][4] = {};
  const int kTiles = K >> 6;
  const size_t ldb = (size_t)K * 2;
  // staging: 4 issues per operand; issue i covers rows i*32 + (tid>>3)
  const int srow = tid >> 3;                                    // 0..31
  const int scol = ((tid & 7) * 16) ^ (((tid >> 3) & 7) << 4);  // pre-swizzled src col
  const char* a_src = (const char*)A + (size_t)(m0 + srow) * ldb + scol;
  const char* b_src = (const char*)BT + (size_t)(n0 + srow) * ldb + scol;
  char* a_d = (char*)Al + wave * 1024;
  char* b_d = (char*)Bl + wave * 1024;
  const size_t row32 = (size_t)32 * ldb;
  for (int kt = 0; kt < kTiles; ++kt) {
    const size_t k0b = (size_t)kt * 128;
    if (kt) __syncthreads();
#pragma unroll
    for (int i = 0; i < 4; ++i) {
      gl2lds16(a_src + i * row32 + k0b, a_d + i * 4096);
      gl2lds16(b_src + i * row32 + k0b, b_d + i * 4096);
    }
    __syncthreads();
    short8 af[4][2], bf2[4][2];
#pragma unroll
    for (int i = 0; i < 4; ++i) {
      const int ra = (wm * 64 + i * 16 + r16) * 128;
      const int rb = (wn * 64 + i * 16 + r16) * 128;
      const int sw = (r16 & 7) << 4;
#pragma unroll
      for (int ks = 0; ks < 2; ++ks) {
        af[i][ks] = *(const short8*)((const char*)Al + ra + ((ks * 64 + g * 16) ^ sw));
        bf2[i][ks] = *(const short8*)((const char*)Bl + rb + ((ks * 64 + g * 16) ^ sw));
      }
    }
#pragma unroll
    for (int ks = 0; ks < 2; ++ks)
#pragma unroll
      for (int mi = 0; mi < 4; ++mi)
#pragma unroll
        for (int ni = 0; ni < 4; ++ni)
          acc[mi][ni] = __builtin_amdgcn_mfma_f32_16x16x32_bf16(af[mi][ks], bf2[ni][ks],
                                                                acc[mi][ni], 0, 0, 0);
  }
#pragma unroll
  for (int mi = 0; mi < 4; ++mi)
#pragma unroll
    for (int ni = 0; ni < 4; ++ni)
#pragma unroll
      for (int r = 0; r < 4; ++r) {
        int row = m0 + wm * 64 + mi * 16 + g * 4 + r;
        int col = n0 + wn * 64 + ni * 16 + r16;
        float v = acc[mi][ni][r];
        if (OUT_MODE == 0) {
          Cb[(size_t)row * N + col] = f2bf(v);
        } else {
          Cf[(size_t)row * N + col] = v + bias[col];
        }
      }
}

// ---------------- MFMA causal flash attention (swapped QK^T, 32x32) ----------------
// 128-thread WGs (2 waves x 32 q-rows), 64-row Q-tiles, grid (16,16,4) = 1024 WGs.
// Pairing qt with 31-qt -> uniform 33 key-blocks/WG; ~6 WGs/CU hide K-DMA latency.
// Two-barrier race-free skeleton; l via mfma(pa, ones).
__global__ __launch_bounds__(128) void attn_mfma_kernel(const ushort* __restrict__ QKV,
                                                        ushort* __restrict__ O) {
  int flat = blockIdx.z * 256 + blockIdx.y * 16 + blockIdx.x;
  flat = (flat & 7) * 128 + (flat >> 3);  // XCD-chunked swizzle (1024 % 8 == 0)
  const int qtA = flat & 15;
  const int h = (flat >> 4) & 15;
  const int b = flat >> 8;
  __shared__ __align__(16) ushort Kl[64 * 64];  // K rows (128B), XOR-swizzled content
  __shared__ __align__(16) ushort VT[64 * 64];  // V^T rows=dim (128B), swizzled
  const int tid = threadIdx.x;
  const int lane = tid & 63;
  const int wave = tid >> 6;  // 0..1
  const int lo5 = lane & 31;
  const int hi = lane >> 5;

  short8 ones;
#pragma unroll
  for (int i = 0; i < 8; ++i) ones[i] = (short)0x3F80;  // bf16 1.0

  // K staging: issue i covers LDS rows i*16 + wave*8 + (lane>>3)
  const int krow_off = wave * 8 + (lane >> 3);
  const int ksrc_col = ((lane & 7) * 16) ^ (((lane >> 3) & 7) << 4);
  const char* kgbase = (const char*)(QKV + ((size_t)b * 2048) * 3072 + 1024 + h * 64);
  // V staging: thread owns key pair kp2 x dim-groups {dg0, dg0+4}
  const int kp2 = (tid & 31) * 2;
  const int dg0 = tid >> 5;  // 0..3
  const char* vgbase = (const char*)(QKV + ((size_t)b * 2048) * 3072 + 2048 + h * 64);

#pragma unroll
  for (int ph = 0; ph < 2; ++ph) {
    const int qt = ph ? qtA : (31 - qtA);
    const int qbase = qt * 64 + wave * 32;
    const int qg = qbase + lo5;

    short8 qf[4];
    {
      const ushort* qp = QKV + ((size_t)(b * 2048 + qbase + lo5) * 3072) + h * 64 + hi * 8;
#pragma unroll
      for (int dc = 0; dc < 4; ++dc) qf[dc] = *(const short8*)(qp + dc * 16);
    }

    f32x16 o0 = {}, o1 = {}, lacc = {};
    const int nblk = qt + 1;

    // prologue: V(0) register prefetch
    uint4 va0, va1, vb0, vb1;
    {
      const char* vp = vgbase + (size_t)kp2 * 6144 + dg0 * 16;
      va0 = *(const uint4*)vp;
      va1 = *(const uint4*)(vp + 6144);
      vb0 = *(const uint4*)(vp + 64);
      vb1 = *(const uint4*)(vp + 6144 + 64);
    }

    for (int blk = 0; blk < nblk; ++blk) {
      const int s0 = blk * 64;
      __syncthreads();  // A: all prior LDS reads drained (lgkmcnt at barrier)
      {                 // stage V(blk): transposed + swizzled, 16 b32 writes
        const ushort* ea0 = (const ushort*)&va0;
        const ushort* ea1 = (const ushort*)&va1;
        const ushort* eb0 = (const ushort*)&vb0;
        const ushort* eb1 = (const ushort*)&vb1;
#pragma unroll
        for (int j = 0; j < 8; ++j) {
          const int col = (kp2 * 2) ^ (j << 4);
          *(unsigned*)((char*)VT + (dg0 * 8 + j) * 128 + col) =
              (unsigned)ea0[j] | ((unsigned)ea1[j] << 16);
          *(unsigned*)((char*)VT + ((dg0 + 4) * 8 + j) * 128 + col) =
              (unsigned)eb0[j] | ((unsigned)eb1[j] << 16);
        }
      }
      // stage K(blk): async DMA, linear dest + pre-swizzled source
#pragma unroll
      for (int i = 0; i < 4; ++i) {
        gl2lds16(kgbase + (size_t)(s0 + i * 16 + krow_off) * 6144 + ksrc_col,
                 (char*)Kl + i * 2048 + wave * 1024);
      }
      __syncthreads();  // B: staging visible (vmcnt+lgkmcnt drained by all waves)

      if (blk + 1 < nblk) {  // prefetch V(blk+1) into regs during compute
        const char* vp = vgbase + (size_t)(s0 + 64 + kp2) * 6144 + dg0 * 16;
        va0 = *(const uint4*)vp;
        va1 = *(const uint4*)(vp + 6144);
        vb0 = *(const uint4*)(vp + 64);
        vb1 = *(const uint4*)(vp + 6144 + 64);
      }

#pragma unroll
      for (int g2 = 0; g2 < 2; ++g2) {
        const int ks = s0 + g2 * 32;
        if (ks > qbase + 31) continue;  // fully masked (wave-uniform)
        f32x16 s_acc = {};
        const int krow = g2 * 32 + lo5;
        const char* ksrc = (const char*)Kl + krow * 128;
        const int ksw = (krow & 7) << 4;
#pragma unroll
        for (int dc = 0; dc < 4; ++dc) {
          short8 kf = *(const short8*)(ksrc + ((dc * 32 + hi * 16) ^ ksw));
          s_acc = __builtin_amdgcn_mfma_f32_32x32x16_bf16(kf, qf[dc], s_acc, 0, 0, 0);
        }
        float p[16];
        if (ks + 31 > qbase) {  // straddling diagonal (wave-uniform branch)
          const int ksg = ks + 4 * hi;
#pragma unroll
          for (int r = 0; r < 16; ++r) {
            const int key_g = ksg + (r & 3) + 8 * (r >> 2);
            float pv = fast_exp2(s_acc[r]);
            p[r] = (key_g <= qg) ? pv : 0.f;
          }
        } else {
#pragma unroll
          for (int r = 0; r < 16; ++r) p[r] = fast_exp2(s_acc[r]);
        }
#pragma unroll
        for (int kc = 0; kc < 2; ++kc) {
          unsigned w0 = cvtpk_bf16(p[kc * 8 + 0], p[kc * 8 + 1]);
          unsigned w2 = cvtpk_bf16(p[kc * 8 + 4], p[kc * 8 + 5]);
          unsigned w1 = cvtpk_bf16(p[kc * 8 + 2], p[kc * 8 + 3]);
          unsigned w3 = cvtpk_bf16(p[kc * 8 + 6], p[kc * 8 + 7]);
          asm("v_permlane32_swap_b32 %0, %1" : "+v"(w0), "+v"(w2));
          asm("v_permlane32_swap_b32 %0, %1" : "+v"(w1), "+v"(w3));
          uint4 paw;
          paw.x = w0; paw.y = w1; paw.z = w2; paw.w = w3;
          short8 pa = *(short8*)&paw;
          const int kb = (g2 * 32 + kc * 16 + hi * 8) * 2;
          lacc = __builtin_amdgcn_mfma_f32_32x32x16_bf16(pa, ones, lacc, 0, 0, 0);
          {
            const int vrow = lo5;
            short8 vf =
                *(const short8*)((const char*)VT + vrow * 128 + (kb ^ ((vrow & 7) << 4)));
            o0 = __builtin_amdgcn_mfma_f32_32x32x16_bf16(pa, vf, o0, 0, 0, 0);
          }
          {
            const int vrow = 32 + lo5;
            short8 vf =
                *(const short8*)((const char*)VT + vrow * 128 + (kb ^ ((vrow & 7) << 4)));
            o1 = __builtin_amdgcn_mfma_f32_32x32x16_bf16(pa, vf, o1, 0, 0, 0);
          }
        }
      }
    }

#pragma unroll
    for (int r = 0; r < 16; ++r) {
      const int qr = (r & 3) + 8 * (r >> 2) + 4 * hi;
      const float li = 1.f / lacc[r];
      ushort* ob = O + ((size_t)(b * 2048 + qbase + qr) * 1024) + h * 64 + lo5;
      ob[0] = f2bf(o0[r] * li);
      ob[32] = f2bf(o1[r] * li);
    }
  }
}

extern "C" void kernel_launch(void* const* d_in, const int* in_sizes, int n_in,
                              void* d_out, int out_size, void* d_ws, size_t ws_size,
                              hipStream_t stream) {
  const float* x = (const float*)d_in[0];
  const float* Wq = (const float*)d_in[1];
  const float* Wk = (const float*)d_in[2];
  const float* Wv = (const float*)d_in[3];
  const float* Wp = (const float*)d_in[4];
  const float* bp = (const float*)d_in[5];
  float* out = (float*)d_out;

  ushort* xb = (ushort*)d_ws;            // [8192,1024]
  ushort* WqkvT = xb + 8388608;          // [3072,1024]
  ushort* WpT = WqkvT + 3145728;         // [1024,1024]
  ushort* QKV = WpT + 1048576;           // [8192,3072]
  ushort* O = QKV + 25165824;            // [8192,1024]

  pack_all_kernel<<<5120, 256, 0, stream>>>(x, Wq, Wk, Wv, Wp, xb, WqkvT, WpT);
  gemm_bt<0><<<dim3(24, 64), 256, 0, stream>>>(xb, WqkvT, QKV, nullptr, nullptr,
                                               8192, 3072, 1024);
  attn_mfma_kernel<<<dim3(16, 16, 4), 128, 0, stream>>>(QKV, O);
  gemm_bt<1><<<dim3(8, 64), 256, 0, stream>>>(O, WpT, nullptr, out, bp,
                                              8192, 1024, 1024);
}

// Round 8
// 154.414 us; speedup vs baseline: 7.6268x; 1.0670x over previous
//
#include <hip/hip_runtime.h>
#include <stdint.h>

// Problem constants: B=4, T=2048, D=1024, H=16, HS=64
typedef __attribute__((ext_vector_type(8))) short short8;
typedef __attribute__((ext_vector_type(4))) float f32x4;
typedef __attribute__((ext_vector_type(16))) float f32x16;

__device__ __forceinline__ unsigned short f2bf(float f) {
  unsigned u = __float_as_uint(f);
  u = u + 0x7FFFu + ((u >> 16) & 1u);  // RNE
  return (unsigned short)(u >> 16);
}
__device__ __forceinline__ unsigned cvtpk_bf16(float lo, float hi) {
  unsigned r;
  asm("v_cvt_pk_bf16_f32 %0, %1, %2" : "=v"(r) : "v"(lo), "v"(hi));
  return r;
}
__device__ __forceinline__ float fast_exp2(float x) {
#if __has_builtin(__builtin_amdgcn_exp2f)
  return __builtin_amdgcn_exp2f(x);
#else
  return exp2f(x);
#endif
}
// async global->LDS, 16B per lane; lds ptr wave-uniform (HW adds lane*16)
__device__ __forceinline__ void gl2lds16(const void* g, void* l) {
  __builtin_amdgcn_global_load_lds(
      (const __attribute__((address_space(1))) void*)(uintptr_t)g,
      (__attribute__((address_space(3))) void*)(uintptr_t)l, 16, 0, 0);
}

// ---------------- fused pack: x -> bf16; weights -> transposed bf16 ----------------
__global__ __launch_bounds__(256) void pack_all_kernel(const float* __restrict__ x,
                                                       const float* __restrict__ Wq,
                                                       const float* __restrict__ Wk,
                                                       const float* __restrict__ Wv,
                                                       const float* __restrict__ Wp,
                                                       ushort* __restrict__ xb,
                                                       ushort* __restrict__ WqkvT,
                                                       ushort* __restrict__ WpT) {
  __shared__ float tile[64][65];
  const int bid0 = blockIdx.x;
  const int tid = threadIdx.x;
  if (bid0 < 4096) {
    int i = (bid0 * 256 + tid) * 8;
    float4 a = *(const float4*)(x + i);
    float4 b = *(const float4*)(x + i + 4);
    uint4 o;
    o.x = (unsigned)f2bf(a.x) | ((unsigned)f2bf(a.y) << 16);
    o.y = (unsigned)f2bf(a.z) | ((unsigned)f2bf(a.w) << 16);
    o.z = (unsigned)f2bf(b.x) | ((unsigned)f2bf(b.y) << 16);
    o.w = (unsigned)f2bf(b.z) | ((unsigned)f2bf(b.w) << 16);
    *(uint4*)(xb + i) = o;
    return;
  }
  const int bid = bid0 - 4096;
  const int lr = tid >> 6;   // 0..3
  const int lc = tid & 63;   // 0..63
  if (bid < 768) {
    const int s = bid >> 8;
    const int rem = bid & 255;
    const int h = rem >> 4;
    const int dt = rem & 15;
    const float* W = (s == 0) ? Wq : (s == 1) ? Wk : Wv;
    const float scale = (s == 0) ? 0.18033688011f : 1.0f;  // 0.125 * log2(e)
#pragma unroll
    for (int p = 0; p < 16; ++p) {
      int r = p * 4 + lr;
      tile[r][lc] = W[(size_t)(h * 1024 + dt * 64 + r) * 64 + lc];
    }
    __syncthreads();
#pragma unroll
    for (int p = 0; p < 16; ++p) {
      int e = p * 4 + lr;
      float v = tile[lc][e] * scale;
      WqkvT[(size_t)(s * 1024 + h * 64 + e) * 1024 + dt * 64 + lc] = f2bf(v);
    }
  } else {
    const int t = bid - 768;
    const int rt = t >> 4, ct = t & 15;
#pragma unroll
    for (int p = 0; p < 16; ++p) {
      int r = p * 4 + lr;
      tile[r][lc] = Wp[(size_t)(rt * 64 + r) * 1024 + ct * 64 + lc];
    }
    __syncthreads();
#pragma unroll
    for (int p = 0; p < 16; ++p) {
      int c = p * 4 + lr;
      float v = tile[lc][c];
      WpT[(size_t)(ct * 64 + c) * 1024 + rt * 64 + lc] = f2bf(v);
    }
  }
}

// ---------------- bf16 MFMA GEMM: C[M,N] = A[M,K] * BT[N,K]^T ----------------
// 128x128 tile, BK=64 (128B LDS rows), 2-barrier skeleton, row-XOR swizzle
// (pre-swizzled gl2lds source + XOR frag read). r7-proven, ~858 TF.
template <int OUT_MODE>
__global__ __launch_bounds__(256) void gemm_bt(const ushort* __restrict__ A,
                                               const ushort* __restrict__ BT,
                                               ushort* __restrict__ Cb,
                                               float* __restrict__ Cf,
                                               const float* __restrict__ bias,
                                               int M, int N, int K) {
  __shared__ __align__(16) ushort Al[128 * 64];
  __shared__ __align__(16) ushort Bl[128 * 64];
  const int tid = threadIdx.x;
  const int lane = tid & 63;
  const int wave = tid >> 6;
  const int wm = wave >> 1, wn = wave & 1;
  const int nbx = gridDim.x;
  const int nwg = nbx * gridDim.y;
  int wg = blockIdx.y * nbx + blockIdx.x;
  wg = (wg & 7) * (nwg >> 3) + (wg >> 3);
  const int m0 = (wg / nbx) * 128, n0 = (wg % nbx) * 128;
  const int r16 = lane & 15, g = lane >> 4;
  f32x4 acc[4][4] = {};
  const int kTiles = K >> 6;
  const size_t ldb = (size_t)K * 2;
  const int srow = tid >> 3;                                    // 0..31
  const int scol = ((tid & 7) * 16) ^ (((tid >> 3) & 7) << 4);  // pre-swizzled src col
  const char* a_src = (const char*)A + (size_t)(m0 + srow) * ldb + scol;
  const char* b_src = (const char*)BT + (size_t)(n0 + srow) * ldb + scol;
  char* a_d = (char*)Al + wave * 1024;
  char* b_d = (char*)Bl + wave * 1024;
  const size_t row32 = (size_t)32 * ldb;
  for (int kt = 0; kt < kTiles; ++kt) {
    const size_t k0b = (size_t)kt * 128;
    if (kt) __syncthreads();
#pragma unroll
    for (int i = 0; i < 4; ++i) {
      gl2lds16(a_src + i * row32 + k0b, a_d + i * 4096);
      gl2lds16(b_src + i * row32 + k0b, b_d + i * 4096);
    }
    __syncthreads();
    short8 af[4][2], bf2[4][2];
#pragma unroll
    for (int i = 0; i < 4; ++i) {
      const int ra = (wm * 64 + i * 16 + r16) * 128;
      const int rb = (wn * 64 + i * 16 + r16) * 128;
      const int sw = (r16 & 7) << 4;
#pragma unroll
      for (int ks = 0; ks < 2; ++ks) {
        af[i][ks] = *(const short8*)((const char*)Al + ra + ((ks * 64 + g * 16) ^ sw));
        bf2[i][ks] = *(const short8*)((const char*)Bl + rb + ((ks * 64 + g * 16) ^ sw));
      }
    }
#pragma unroll
    for (int ks = 0; ks < 2; ++ks)
#pragma unroll
      for (int mi = 0; mi < 4; ++mi)
#pragma unroll
        for (int ni = 0; ni < 4; ++ni)
          acc[mi][ni] = __builtin_amdgcn_mfma_f32_16x16x32_bf16(af[mi][ks], bf2[ni][ks],
                                                                acc[mi][ni], 0, 0, 0);
  }
#pragma unroll
  for (int mi = 0; mi < 4; ++mi)
#pragma unroll
    for (int ni = 0; ni < 4; ++ni)
#pragma unroll
      for (int r = 0; r < 4; ++r) {
        int row = m0 + wm * 64 + mi * 16 + g * 4 + r;
        int col = n0 + wn * 64 + ni * 16 + r16;
        float v = acc[mi][ni][r];
        if (OUT_MODE == 0) {
          Cb[(size_t)row * N + col] = f2bf(v);
        } else {
          Cf[(size_t)row * N + col] = v + bias[col];
        }
      }
}

// ---------------- MFMA causal flash attention (swapped QK^T, 32x32) ----------------
// r6-proven 256-thread skeleton (4 waves x 32 q-rows, 128-row Q-tiles, grid 512,
// pairing 15-qtA/qtA -> uniform 34 blocks) + K DOUBLE-BUFFER:
//   K(blk+1) DMA issued right after barrier B(blk) into Kl[cur^1]; it drains at
//   barrier A(blk+1), i.e. hidden under block-blk compute. Race-free under plain
//   __syncthreads drain semantics: Kl[cur^1]'s last readers finished before A(blk).
// V single-buffered: reg-prefetch during compute, ds_write in the A->B window.
__global__ __launch_bounds__(256) void attn_mfma_kernel(const ushort* __restrict__ QKV,
                                                        ushort* __restrict__ O) {
  int flat = blockIdx.z * 128 + blockIdx.y * 8 + blockIdx.x;
  flat = (flat & 7) * 64 + (flat >> 3);  // XCD-chunked swizzle
  const int qtA = flat & 7;
  const int h = (flat >> 3) & 15;
  const int b = flat >> 7;
  __shared__ __align__(16) ushort Kl[2][64 * 64];  // K rows, XOR-swizzled content
  __shared__ __align__(16) ushort VT[64 * 64];     // V^T [dim][key], swizzled
  const int tid = threadIdx.x;
  const int lane = tid & 63;
  const int wave = tid >> 6;
  const int lo5 = lane & 31;
  const int hi = lane >> 5;

  short8 ones;
#pragma unroll
  for (int i = 0; i < 8; ++i) ones[i] = (short)0x3F80;  // bf16 1.0

  const int k_key0 = wave * 16 + (lane >> 3);
  const int k_key1 = k_key0 + 8;
  const int ksrc_off0 = ((lane & 7) * 16) ^ ((k_key0 & 7) << 4);
  const int ksrc_off1 = ((lane & 7) * 16) ^ ((k_key1 & 7) << 4);
  const char* kgbase = (const char*)(QKV + ((size_t)b * 2048) * 3072 + 1024 + h * 64);
  const int kp2 = (tid & 31) * 2;
  const int dg = tid >> 5;
  const char* vgbase = (const char*)(QKV + ((size_t)b * 2048) * 3072 + 2048 + h * 64 + dg * 8);

#pragma unroll
  for (int ph = 0; ph < 2; ++ph) {
    const int qt = ph ? qtA : (15 - qtA);
    const int qbase = qt * 128 + wave * 32;
    const int qg = qbase + lo5;

    short8 qf[4];
    {
      const ushort* qp = QKV + ((size_t)(b * 2048 + qbase + lo5) * 3072) + h * 64 + hi * 8;
#pragma unroll
      for (int dc = 0; dc < 4; ++dc) qf[dc] = *(const short8*)(qp + dc * 16);
    }

    f32x16 o0 = {}, o1 = {}, lacc = {};
    const int nblk = qt * 2 + 2;

    // prologue: V(0) reg loads; then (after protecting Kl[0]) issue K(0) DMA
    uint4 nv0, nv1;
    {
      const char* vp = vgbase + (size_t)kp2 * 6144;
      nv0 = *(const uint4*)(vp);
      nv1 = *(const uint4*)(vp + 6144);
    }
    __syncthreads();  // previous phase's readers of Kl[0] are done
    gl2lds16(kgbase + (size_t)k_key0 * 6144 + ksrc_off0, (char*)Kl[0] + wave * 2048);
    gl2lds16(kgbase + (size_t)k_key1 * 6144 + ksrc_off1, (char*)Kl[0] + wave * 2048 + 1024);

    int cur = 0;
    for (int blk = 0; blk < nblk; ++blk) {
      const int s0 = blk * 64;
      __syncthreads();  // A: K(blk) DMA drained; block blk-1 LDS reads done
      {                 // stage V(blk) from prefetched regs (transposed, swizzled)
        const ushort* e0 = (const ushort*)&nv0;
        const ushort* e1 = (const ushort*)&nv1;
#pragma unroll
        for (int j = 0; j < 8; ++j) {
          const int row = dg * 8 + j;
          *(unsigned*)((char*)VT + row * 128 + ((kp2 * 2) ^ ((row & 7) << 4))) =
              (unsigned)e0[j] | ((unsigned)e1[j] << 16);
        }
      }
      __syncthreads();  // B: V writes visible (K(blk) visible since A)

      if (blk + 1 < nblk) {
        // issue K(blk+1) DMA now -> latency covered by this block's compute
        char* kd = (char*)Kl[cur ^ 1] + wave * 2048;
        gl2lds16(kgbase + (size_t)(s0 + 64 + k_key0) * 6144 + ksrc_off0, kd);
        gl2lds16(kgbase + (size_t)(s0 + 64 + k_key1) * 6144 + ksrc_off1, kd + 1024);
        // V(blk+1) reg prefetch
        const char* vp = vgbase + (size_t)(s0 + 64 + kp2) * 6144;
        nv0 = *(const uint4*)(vp);
        nv1 = *(const uint4*)(vp + 6144);
      }

      const ushort* Kb = Kl[cur];
#pragma unroll
      for (int g2 = 0; g2 < 2; ++g2) {
        const int ks = s0 + g2 * 32;
        if (ks > qbase + 31) continue;  // fully masked (wave-uniform)
        f32x16 s_acc = {};
        const int krow = g2 * 32 + lo5;
        const char* ksrc = (const char*)Kb + krow * 128;
        const int ksw = (krow & 7) << 4;
#pragma unroll
        for (int dc = 0; dc < 4; ++dc) {
          short8 kf = *(const short8*)(ksrc + ((dc * 32 + hi * 16) ^ ksw));
          s_acc = __builtin_amdgcn_mfma_f32_32x32x16_bf16(kf, qf[dc], s_acc, 0, 0, 0);
        }
        float p[16];
        if (ks + 31 > qbase) {  // straddling diagonal (wave-uniform branch)
          const int ksg = ks + 4 * hi;
#pragma unroll
          for (int r = 0; r < 16; ++r) {
            const int key_g = ksg + (r & 3) + 8 * (r >> 2);
            float pv = fast_exp2(s_acc[r]);
            p[r] = (key_g <= qg) ? pv : 0.f;
          }
        } else {
#pragma unroll
          for (int r = 0; r < 16; ++r) p[r] = fast_exp2(s_acc[r]);
        }
#pragma unroll
        for (int kc = 0; kc < 2; ++kc) {
          unsigned w0 = cvtpk_bf16(p[kc * 8 + 0], p[kc * 8 + 1]);
          unsigned w2 = cvtpk_bf16(p[kc * 8 + 4], p[kc * 8 + 5]);
          unsigned w1 = cvtpk_bf16(p[kc * 8 + 2], p[kc * 8 + 3]);
          unsigned w3 = cvtpk_bf16(p[kc * 8 + 6], p[kc * 8 + 7]);
          asm("v_permlane32_swap_b32 %0, %1" : "+v"(w0), "+v"(w2));
          asm("v_permlane32_swap_b32 %0, %1" : "+v"(w1), "+v"(w3));
          uint4 paw;
          paw.x = w0; paw.y = w1; paw.z = w2; paw.w = w3;
          short8 pa = *(short8*)&paw;
          const int kb = (g2 * 32 + kc * 16 + hi * 8) * 2;
          lacc = __builtin_amdgcn_mfma_f32_32x32x16_bf16(pa, ones, lacc, 0, 0, 0);
          {
            const int vrow = lo5;
            short8 vf =
                *(const short8*)((const char*)VT + vrow * 128 + (kb ^ ((vrow & 7) << 4)));
            o0 = __builtin_amdgcn_mfma_f32_32x32x16_bf16(pa, vf, o0, 0, 0, 0);
          }
          {
            const int vrow = 32 + lo5;
            short8 vf =
                *(const short8*)((const char*)VT + vrow * 128 + (kb ^ ((vrow & 7) << 4)));
            o1 = __builtin_amdgcn_mfma_f32_32x32x16_bf16(pa, vf, o1, 0, 0, 0);
          }
        }
      }
      cur ^= 1;
    }

#pragma unroll
    for (int r = 0; r < 16; ++r) {
      const int qr = (r & 3) + 8 * (r >> 2) + 4 * hi;
      const float li = 1.f / lacc[r];
      ushort* ob = O + ((size_t)(b * 2048 + qbase + qr) * 1024) + h * 64 + lo5;
      ob[0] = f2bf(o0[r] * li);
      ob[32] = f2bf(o1[r] * li);
    }
  }
}

extern "C" void kernel_launch(void* const* d_in, const int* in_sizes, int n_in,
                              void* d_out, int out_size, void* d_ws, size_t ws_size,
                              hipStream_t stream) {
  const float* x = (const float*)d_in[0];
  const float* Wq = (const float*)d_in[1];
  const float* Wk = (const float*)d_in[2];
  const float* Wv = (const float*)d_in[3];
  const float* Wp = (const float*)d_in[4];
  const float* bp = (const float*)d_in[5];
  float* out = (float*)d_out;

  ushort* xb = (ushort*)d_ws;            // [8192,1024]
  ushort* WqkvT = xb + 8388608;          // [3072,1024]
  ushort* WpT = WqkvT + 3145728;         // [1024,1024]
  ushort* QKV = WpT + 1048576;           // [8192,3072]
  ushort* O = QKV + 25165824;            // [8192,1024]

  pack_all_kernel<<<5120, 256, 0, stream>>>(x, Wq, Wk, Wv, Wp, xb, WqkvT, WpT);
  gemm_bt<0><<<dim3(24, 64), 256, 0, stream>>>(xb, WqkvT, QKV, nullptr, nullptr,
                                               8192, 3072, 1024);
  attn_mfma_kernel<<<dim3(8, 16, 4), 256, 0, stream>>>(QKV, O);
  gemm_bt<1><<<dim3(8, 64), 256, 0, stream>>>(O, WpT, nullptr, out, bp,
                                              8192, 1024, 1024);
}